// Round 14
// baseline (173.531 us; speedup 1.0000x reference)
//
#include <hip/hip_runtime.h>
#include <hip/hip_bf16.h>

typedef __hip_bfloat16 bf16;
typedef __attribute__((ext_vector_type(8))) short short8;
typedef __attribute__((ext_vector_type(4))) short sh4;
typedef __attribute__((ext_vector_type(4))) float f32x4;

static __device__ __forceinline__ float bf2f(bf16 h) { return __bfloat162float(h); }
static __device__ __forceinline__ short f2bfs(float f) {
    bf16 h = __float2bfloat16(f);
    return *reinterpret_cast<short*>(&h);
}
static __device__ __forceinline__ float s2f(short s) {
    return bf2f(*reinterpret_cast<bf16*>(&s));
}
static __device__ __forceinline__ short8 cvt8(float4 a, float4 b) {
    short8 o;
    o[0] = f2bfs(a.x); o[1] = f2bfs(a.y); o[2] = f2bfs(a.z); o[3] = f2bfs(a.w);
    o[4] = f2bfs(b.x); o[5] = f2bfs(b.y); o[6] = f2bfs(b.z); o[7] = f2bfs(b.w);
    return o;
}

constexpr int Bn = 8;
constexpr int C  = 256;
constexpr int N  = 1024;     // H*W
constexpr int NH = 8;
constexpr int HD = 32;
constexpr int TS = 264;      // LDS tile stride (shorts)
constexpr float SCALE = 0.17677669529663687f;  // 1/sqrt(32)

// ---------------------------------------------------------------------------
// K0: convert Wq|Wk|Wv|Wp f32 -> Wb bf16 [4][256][256]. 16 blocks.
// ---------------------------------------------------------------------------
__global__ __launch_bounds__(256) void k_prep(
    const float* __restrict__ Wq, const float* __restrict__ Wk,
    const float* __restrict__ Wv, const float* __restrict__ Wp,
    bf16* __restrict__ Wb)
{
    const int tid = threadIdx.x;
    const int mat = blockIdx.x >> 2, seg = blockIdx.x & 3;
    const float* src = (mat == 0) ? Wq : (mat == 1) ? Wk : (mat == 2) ? Wv : Wp;
    short* dst = reinterpret_cast<short*>(Wb) + (size_t)mat * 256 * 256;
#pragma unroll
    for (int i = 0; i < 16; ++i) {
        int f4 = seg * 4096 + i * 256 + tid;
        float4 v = reinterpret_cast<const float4*>(src)[f4];
        sh4 o;
        o[0] = f2bfs(v.x); o[1] = f2bfs(v.y); o[2] = f2bfs(v.z); o[3] = f2bfs(v.w);
        *reinterpret_cast<sh4*>(dst + (size_t)f4 * 4) = o;
    }
}

// ---------------------------------------------------------------------------
// K1: fused transpose + gates + q/k/v GEMM, M-SPLIT.
// grid 1024 = (b, 16-px tile, m-half) -> 4 blocks/CU. Identical inner loop
// to R12 but 6 m-frags/wave. v rows also written pixel-major (v_pm) for the
// reduce kernel's gating.
// ---------------------------------------------------------------------------
__global__ __launch_bounds__(256) void k_fused3(
    const float* __restrict__ x, const float* __restrict__ gq, const float* __restrict__ gk,
    const float* __restrict__ Wsq, const float* __restrict__ bsq,
    const float* __restrict__ Wsk, const float* __restrict__ bsk,
    const bf16* __restrict__ Wb,
    const float* __restrict__ bq, const float* __restrict__ bk, const float* __restrict__ bv,
    bf16* __restrict__ qo, bf16* __restrict__ ko, bf16* __restrict__ vo,
    bf16* __restrict__ v_pm, float* __restrict__ sqg)
{
    __shared__ short T[16 * TS];     // [pixel][c]
    __shared__ float sq_lds[16];
    __shared__ float sk_lds[16];

    const int tid  = threadIdx.x;
    const int wave = tid >> 6;
    const int lane = tid & 63;
    const int col  = lane & 15;
    const int quad = lane >> 4;

    const int b     = blockIdx.x >> 7;
    const int rest  = blockIdx.x & 127;
    const int n0    = (rest >> 1) * 16;
    const int mhalf = rest & 1;

    // ---- stage x^T tile: 256 c-rows x 16 pixels ----
    {
        const float* xp = x + (size_t)b * C * N + n0;
        const int cr = tid >> 2;
        const int f  = tid & 3;
#pragma unroll
        for (int p = 0; p < 4; ++p) {
            int c = p * 64 + cr;
            float4 v = *reinterpret_cast<const float4*>(xp + (size_t)c * N + f * 4);
            T[(f * 4 + 0) * TS + c] = f2bfs(v.x);
            T[(f * 4 + 1) * TS + c] = f2bfs(v.y);
            T[(f * 4 + 2) * TS + c] = f2bfs(v.z);
            T[(f * 4 + 3) * TS + c] = f2bfs(v.w);
        }
    }
    __syncthreads();

    // ---- gates (wave 0): logits via one MFMA, lane-local softmax ----
    if (wave == 0) {
        const float* wsrc = (col < 4) ? (Wsq + col * C) : (Wsk + (col & 3) * C);
        f32x4 ga = {};
#pragma unroll
        for (int k0 = 0; k0 < 256; k0 += 32) {
            float4 w0 = *reinterpret_cast<const float4*>(wsrc + k0 + quad * 8);
            float4 w1 = *reinterpret_cast<const float4*>(wsrc + k0 + quad * 8 + 4);
            short8 af = cvt8(w0, w1);
            short8 b0 = *reinterpret_cast<const short8*>(&T[col * TS + k0 + quad * 8]);
            ga = __builtin_amdgcn_mfma_f32_16x16x32_bf16(af, b0, ga, 0, 0, 0);
        }
        if (quad < 2) {
            const float* bsrc = (quad == 0) ? bsq : bsk;
            const float* gsrc = (quad == 0) ? gq : gk;
            int n = n0 + col;
            float a[4];
#pragma unroll
            for (int r = 0; r < 4; ++r)
                a[r] = ga[r] + bsrc[r] + gsrc[(size_t)b * 4 * N + (size_t)r * N + n];
            float mx = fmaxf(fmaxf(a[0], a[1]), fmaxf(a[2], a[3]));
            float e = 0.f;
#pragma unroll
            for (int r = 0; r < 4; ++r) e += __expf(a[r] - mx);
            float p0 = __expf(a[0] - mx) / e;
            if (quad == 0) {
                sq_lds[col] = p0;
                if (mhalf == 0) sqg[b * N + n] = p0;
            } else {
                sk_lds[col] = p0;
            }
        }
    }
    __syncthreads();

    // ---- GEMM: this block's M half (384 rows), 6 m-frags per wave ----
    const short* Ws = reinterpret_cast<const short*>(Wb);
    const int mwbase = mhalf * 384 + wave * 96;
    f32x4 acc[6] = {};
#pragma unroll
    for (int k0 = 0; k0 < 256; k0 += 32) {
        short8 b0 = *reinterpret_cast<const short8*>(&T[col * TS + k0 + quad * 8]);
#pragma unroll
        for (int i = 0; i < 6; ++i) {
            int m = mwbase + i * 16;
            const short* wr = Ws + (size_t)(m >> 8) * 65536
                              + (size_t)((m & 255) + col) * 256 + k0 + quad * 8;
            short8 af = *reinterpret_cast<const short8*>(wr);
            acc[i] = __builtin_amdgcn_mfma_f32_16x16x32_bf16(af, b0, acc[i], 0, 0, 0);
        }
    }
    // epilogue
    const int n = n0 + col;
#pragma unroll
    for (int i = 0; i < 6; ++i) {
        int m = mwbase + i * 16;
        int mat = m >> 8;
        int cr  = (m & 255) + quad * 4;
        const float* bb = (mat == 0) ? bq : (mat == 1) ? bk : bv;
        float bias[4];
#pragma unroll
        for (int r = 0; r < 4; ++r) bias[r] = bb[cr + r];
        if (mat < 2) {
            float g = (mat == 0) ? sq_lds[col] * SCALE : sk_lds[col];
            short* op = reinterpret_cast<short*>((mat == 0) ? qo : ko) + (size_t)b * N * C;
            sh4 pack;
#pragma unroll
            for (int r = 0; r < 4; ++r) pack[r] = f2bfs((acc[i][r] + bias[r]) * g);
            *reinterpret_cast<sh4*>(op + (size_t)n * C + cr) = pack;
        } else {
            bf16* op = vo + (size_t)b * C * N;
            sh4 pack;
#pragma unroll
            for (int r = 0; r < 4; ++r) {
                float v = acc[i][r] + bias[r];
                op[(size_t)(cr + r) * N + n] = __float2bfloat16(v);
                pack[r] = f2bfs(v);
            }
            *reinterpret_cast<sh4*>(reinterpret_cast<short*>(v_pm) + ((size_t)b * N + n) * C + cr) = pack;
        }
    }
}

// ---------------------------------------------------------------------------
// K2: attention, K-SPLIT. grid 1024 = (b, head, 128-q tile, k-half) ->
// 4 blocks/CU. Identical 2-Q-frag inner loop over 512 keys. Writes RAW
// partial sums: o_part f32 pixel-major, l_part f32. No max-subtraction
// needed (|s|<0.1), so halves combine exactly in k_reduce.
// ---------------------------------------------------------------------------
__global__ __launch_bounds__(256) void k_attn5(
    const bf16* __restrict__ qo, const bf16* __restrict__ ko,
    const bf16* __restrict__ vo,
    float* __restrict__ o_part, float* __restrict__ l_part)
{
    __shared__ short P_lds[4][32 * 72];   // 36.9 KB

    const int tid  = threadIdx.x;
    const int wave = tid >> 6;
    const int lane = tid & 63;
    const int col  = lane & 15;
    const int quad = lane >> 4;

    const int khalf = blockIdx.x & 1;
    const int qt    = (blockIdx.x >> 1) & 7;
    const int h     = (blockIdx.x >> 4) & 7;
    const int b     = blockIdx.x >> 7;
    const int qbase = qt * 128 + wave * 32;
    const int ks    = khalf * 512;

    const short* kp = reinterpret_cast<const short*>(ko) + (size_t)b * N * C + h * HD + quad * 8;
    const short* vp = reinterpret_cast<const short*>(vo) + (size_t)b * C * N + (size_t)h * HD * N;

    short8 qf[2];
    {
        const short* qp = reinterpret_cast<const short*>(qo) + (size_t)b * N * C + h * HD + quad * 8;
#pragma unroll
        for (int g = 0; g < 2; ++g)
            qf[g] = *reinterpret_cast<const short8*>(qp + (size_t)(qbase + g * 16 + col) * C);
    }

    float l[2] = {};
    f32x4 oac[2][2] = {};   // [g][dh]
    short* P = P_lds[wave];

    short8 kf[4];
#pragma unroll
    for (int c = 0; c < 4; ++c)
        kf[c] = *reinterpret_cast<const short8*>(kp + (size_t)(ks + c * 16 + col) * C);

    for (int kb = ks; kb < ks + 512; kb += 64) {
        short8 vf[2][2];
#pragma unroll
        for (int kg = 0; kg < 2; ++kg)
#pragma unroll
            for (int dh = 0; dh < 2; ++dh)
                vf[kg][dh] = *reinterpret_cast<const short8*>(vp + (size_t)(dh * 16 + col) * N + kb + kg * 32 + quad * 8);

#pragma unroll
        for (int g = 0; g < 2; ++g) {
            float s[16];
#pragma unroll
            for (int c = 0; c < 4; ++c) {
                f32x4 acc = {};
                acc = __builtin_amdgcn_mfma_f32_16x16x32_bf16(kf[c], qf[g], acc, 0, 0, 0);
#pragma unroll
                for (int r = 0; r < 4; ++r) s[c * 4 + r] = acc[r];
            }
            float p[16], lloc = 0.f;
#pragma unroll
            for (int i = 0; i < 16; ++i) { p[i] = __expf(s[i]); lloc += p[i]; }
            lloc += __shfl_xor(lloc, 16, 64);
            lloc += __shfl_xor(lloc, 32, 64);
            l[g] += lloc;
#pragma unroll
            for (int c = 0; c < 4; ++c) {
                sh4 pk;
#pragma unroll
                for (int r = 0; r < 4; ++r) pk[r] = f2bfs(p[c * 4 + r]);
                *reinterpret_cast<sh4*>(&P[(g * 16 + col) * 72 + c * 16 + quad * 4]) = pk;
            }
        }

        const int kn = ks + ((kb - ks + 64) & 511);
#pragma unroll
        for (int c = 0; c < 4; ++c)
            kf[c] = *reinterpret_cast<const short8*>(kp + (size_t)(kn + c * 16 + col) * C);

#pragma unroll
        for (int kg = 0; kg < 2; ++kg) {
#pragma unroll
            for (int g = 0; g < 2; ++g) {
                short8 pf = *reinterpret_cast<const short8*>(&P[(g * 16 + col) * 72 + kg * 32 + quad * 8]);
#pragma unroll
                for (int dh = 0; dh < 2; ++dh)
                    oac[g][dh] = __builtin_amdgcn_mfma_f32_16x16x32_bf16(vf[kg][dh], pf, oac[g][dh], 0, 0, 0);
            }
        }
    }

    // epilogue: raw partial sums, pixel-major f32
#pragma unroll
    for (int g = 0; g < 2; ++g) {
        const int q = qbase + g * 16 + col;
        float* op = o_part + (((size_t)khalf * Bn + b) * N + q) * C + h * HD + quad * 4;
#pragma unroll
        for (int dh = 0; dh < 2; ++dh) {
            float4 pack;
            pack.x = oac[g][dh][0]; pack.y = oac[g][dh][1];
            pack.z = oac[g][dh][2]; pack.w = oac[g][dh][3];
            *reinterpret_cast<float4*>(op + dh * 16) = pack;
        }
        if (quad == 0)
            l_part[(((size_t)khalf * Bn + b) * NH + h) * N + q] = l[g];
    }
}

// ---------------------------------------------------------------------------
// K3: reduce + gate. gt[b][q][c] = sq*(o1+o2)[c]/(l1+l2) + (1-sq)*v_pm.
// 512 blocks x 256 threads; thread = (pixel, 16-channel group). Pure
// streaming (~25 MB).
// ---------------------------------------------------------------------------
__global__ __launch_bounds__(256) void k_reduce(
    const float* __restrict__ o_part, const float* __restrict__ l_part,
    const bf16* __restrict__ v_pm, const float* __restrict__ sqg,
    bf16* __restrict__ gt)
{
    const int tid = threadIdx.x;
    const int P   = blockIdx.x * 16 + (tid >> 4);
    const int b   = P >> 10;
    const int q   = P & 1023;
    const int c0  = (tid & 15) * 16;
    const int h   = c0 >> 5;

    const float l12 = l_part[(((size_t)0 * Bn + b) * NH + h) * N + q]
                    + l_part[(((size_t)1 * Bn + b) * NH + h) * N + q];
    const float invl = 1.f / l12;
    const float sqv = sqg[b * N + q];
    const float hv  = 1.f - sqv;

    const float* o1 = o_part + ((size_t)b * N + q) * C + c0;
    const float* o2 = o_part + (((size_t)Bn + b) * N + q) * C + c0;
    const short* vp = reinterpret_cast<const short*>(v_pm) + ((size_t)b * N + q) * C + c0;
    short* gp = reinterpret_cast<short*>(gt) + ((size_t)b * N + q) * C + c0;

#pragma unroll
    for (int u = 0; u < 2; ++u) {
        short8 vv = *reinterpret_cast<const short8*>(vp + u * 8);
        short8 og;
#pragma unroll
        for (int j = 0; j < 8; j += 4) {
            float4 a = *reinterpret_cast<const float4*>(o1 + u * 8 + j);
            float4 c = *reinterpret_cast<const float4*>(o2 + u * 8 + j);
            og[j + 0] = f2bfs(sqv * ((a.x + c.x) * invl) + hv * s2f(vv[j + 0]));
            og[j + 1] = f2bfs(sqv * ((a.y + c.y) * invl) + hv * s2f(vv[j + 1]));
            og[j + 2] = f2bfs(sqv * ((a.z + c.z) * invl) + hv * s2f(vv[j + 2]));
            og[j + 3] = f2bfs(sqv * ((a.w + c.w) * invl) + hv * s2f(vv[j + 3]));
        }
        *reinterpret_cast<short8*>(gp + u * 8) = og;
    }
}

// ---------------------------------------------------------------------------
// K4: projection MFMA GEMM (R6/R12-proven). grid (4, 32, 8) = 1024 blocks.
// ---------------------------------------------------------------------------
__global__ __launch_bounds__(256) void k_projm2(
    const bf16* __restrict__ gt, const bf16* __restrict__ Wpb,
    const float* __restrict__ bp, float* __restrict__ out)
{
    const int tid  = threadIdx.x;
    const int wave = tid >> 6, lane = tid & 63;
    const int col  = lane & 15, quad = lane >> 4;
    const int mrow = blockIdx.x * 64;
    const int b    = blockIdx.z;
    const int n0   = blockIdx.y * 32;

    const short* Wm = reinterpret_cast<const short*>(Wpb);
    const short* gp = reinterpret_cast<const short*>(gt) + (size_t)b * N * C;
    const int m16 = mrow + wave * 16;

    f32x4 acc[2] = {};
#pragma unroll
    for (int k0 = 0; k0 < 256; k0 += 32) {
        short8 af = *reinterpret_cast<const short8*>(Wm + (size_t)(m16 + col) * 256 + k0 + quad * 8);
#pragma unroll
        for (int cf = 0; cf < 2; ++cf) {
            short8 bfr = *reinterpret_cast<const short8*>(gp + (size_t)(n0 + cf * 16 + col) * C + k0 + quad * 8);
            acc[cf] = __builtin_amdgcn_mfma_f32_16x16x32_bf16(af, bfr, acc[cf], 0, 0, 0);
        }
    }

    float bias[4];
#pragma unroll
    for (int r = 0; r < 4; ++r) bias[r] = bp[m16 + quad * 4 + r];
    float* op = out + (size_t)b * C * N;
#pragma unroll
    for (int cf = 0; cf < 2; ++cf) {
        int n = n0 + cf * 16 + col;
#pragma unroll
        for (int r = 0; r < 4; ++r) {
            int c = m16 + quad * 4 + r;
            op[(size_t)c * N + n] = acc[cf][r] + bias[r];
        }
    }
}

// ---------------------------------------------------------------------------
// Workspace (bytes):
//   [0, 32K)     sqg f32 [8][1024]
//   +32K         Wb bf16 [4][256][256]            (512K)
//   +512K        qo bf16 [8][1024][256] pixel-major (4M)
//   +4M          ko bf16 [8][1024][256] pixel-major (4M)
//   +4M          vo bf16 [8][256][1024] d-major     (4M)
//   +4M          v_pm bf16 [8][1024][256] pixel-major (4M)
//   +4M          o_part f32 [2][8][1024][256]     (16.8M)
//   +16.8M       l_part f32 [2][8][8][1024]       (512K)
//   +512K        gt bf16 [8][1024][256]           (4M)
// total ~38 MB
// ---------------------------------------------------------------------------
extern "C" void kernel_launch(void* const* d_in, const int* in_sizes, int n_in,
                              void* d_out, int out_size, void* d_ws, size_t ws_size,
                              hipStream_t stream)
{
    const float* x   = (const float*)d_in[0];
    const float* gq  = (const float*)d_in[1];
    const float* gk  = (const float*)d_in[2];
    const float* Wsq = (const float*)d_in[3];
    const float* bsq = (const float*)d_in[4];
    const float* Wsk = (const float*)d_in[5];
    const float* bsk = (const float*)d_in[6];
    const float* Wq  = (const float*)d_in[7];
    const float* bq  = (const float*)d_in[8];
    const float* Wk  = (const float*)d_in[9];
    const float* bk  = (const float*)d_in[10];
    const float* Wv  = (const float*)d_in[11];
    const float* bv  = (const float*)d_in[12];
    const float* Wp  = (const float*)d_in[13];
    const float* bp  = (const float*)d_in[14];

    char* ws = (char*)d_ws;
    size_t off = 0;
    float* sqg = (float*)(ws + off);            off += 32768;
    bf16* Wb   = (bf16*)(ws + off);             off += 524288;
    bf16* qo   = (bf16*)(ws + off);             off += (size_t)Bn * N * C * 2;
    bf16* ko   = (bf16*)(ws + off);             off += (size_t)Bn * N * C * 2;
    bf16* vo   = (bf16*)(ws + off);             off += (size_t)Bn * C * N * 2;
    bf16* v_pm = (bf16*)(ws + off);             off += (size_t)Bn * N * C * 2;
    float* o_part = (float*)(ws + off);         off += (size_t)2 * Bn * N * C * 4;
    float* l_part = (float*)(ws + off);         off += (size_t)2 * Bn * NH * N * 4;
    bf16* gt   = (bf16*)(ws + off);             off += (size_t)Bn * N * C * 2;
    float* out = (float*)d_out;

    k_prep<<<16, 256, 0, stream>>>(Wq, Wk, Wv, Wp, Wb);
    k_fused3<<<1024, 256, 0, stream>>>(x, gq, gk, Wsq, bsq, Wsk, bsk,
                                       Wb, bq, bk, bv, qo, ko, vo, v_pm, sqg);
    k_attn5<<<1024, 256, 0, stream>>>(qo, ko, vo, o_part, l_part);
    k_reduce<<<512, 256, 0, stream>>>(o_part, l_part, v_pm, sqg, gt);
    k_projm2<<<dim3(4, 32, 8), 256, 0, stream>>>(gt, Wb + 3 * 65536, bp, out);
}

// Round 15
// 166.150 us; speedup vs baseline: 1.0444x; 1.0444x over previous
//
#include <hip/hip_runtime.h>
#include <hip/hip_bf16.h>

typedef __hip_bfloat16 bf16;
typedef __attribute__((ext_vector_type(8))) short short8;
typedef __attribute__((ext_vector_type(4))) short sh4;
typedef __attribute__((ext_vector_type(4))) float f32x4;

static __device__ __forceinline__ float bf2f(bf16 h) { return __bfloat162float(h); }
static __device__ __forceinline__ short f2bfs(float f) {
    bf16 h = __float2bfloat16(f);
    return *reinterpret_cast<short*>(&h);
}
static __device__ __forceinline__ short8 cvt8(float4 a, float4 b) {
    short8 o;
    o[0] = f2bfs(a.x); o[1] = f2bfs(a.y); o[2] = f2bfs(a.z); o[3] = f2bfs(a.w);
    o[4] = f2bfs(b.x); o[5] = f2bfs(b.y); o[6] = f2bfs(b.z); o[7] = f2bfs(b.w);
    return o;
}

constexpr int Bn = 8;
constexpr int C  = 256;
constexpr int N  = 1024;     // H*W
constexpr int NH = 8;
constexpr int HD = 32;
constexpr int TS = 264;      // LDS tile stride (shorts)
constexpr float SCALE = 0.17677669529663687f;  // 1/sqrt(32)

// ---------------------------------------------------------------------------
// K0: convert Wq|Wk|Wv|Wp f32 -> Wb bf16 [4][256][256]. 16 blocks.
// ---------------------------------------------------------------------------
__global__ __launch_bounds__(256) void k_prep(
    const float* __restrict__ Wq, const float* __restrict__ Wk,
    const float* __restrict__ Wv, const float* __restrict__ Wp,
    bf16* __restrict__ Wb)
{
    const int tid = threadIdx.x;
    const int mat = blockIdx.x >> 2, seg = blockIdx.x & 3;
    const float* src = (mat == 0) ? Wq : (mat == 1) ? Wk : (mat == 2) ? Wv : Wp;
    short* dst = reinterpret_cast<short*>(Wb) + (size_t)mat * 256 * 256;
#pragma unroll
    for (int i = 0; i < 16; ++i) {
        int f4 = seg * 4096 + i * 256 + tid;
        float4 v = reinterpret_cast<const float4*>(src)[f4];
        sh4 o;
        o[0] = f2bfs(v.x); o[1] = f2bfs(v.y); o[2] = f2bfs(v.z); o[3] = f2bfs(v.w);
        *reinterpret_cast<sh4*>(dst + (size_t)f4 * 4) = o;
    }
}

// ---------------------------------------------------------------------------
// K1: fused transpose + gates + q/k/v GEMM. 512 blocks = (b, 16-px tile),
// 2 blocks/CU. x read once. Wave computes 12 m-frags (192 rows of M=768)
// with single-b128 A-frags from Wb; B-frag from the LDS x-tile.
// ---------------------------------------------------------------------------
__global__ __launch_bounds__(256) void k_fused3(
    const float* __restrict__ x, const float* __restrict__ gq, const float* __restrict__ gk,
    const float* __restrict__ Wsq, const float* __restrict__ bsq,
    const float* __restrict__ Wsk, const float* __restrict__ bsk,
    const bf16* __restrict__ Wb,
    const float* __restrict__ bq, const float* __restrict__ bk, const float* __restrict__ bv,
    bf16* __restrict__ qo, bf16* __restrict__ ko, bf16* __restrict__ vo,
    float* __restrict__ sqg)
{
    __shared__ short T[16 * TS];     // [pixel][c]
    __shared__ float sq_lds[16];
    __shared__ float sk_lds[16];

    const int tid  = threadIdx.x;
    const int wave = tid >> 6;
    const int lane = tid & 63;
    const int col  = lane & 15;
    const int quad = lane >> 4;

    const int b  = blockIdx.x >> 6;
    const int n0 = (blockIdx.x & 63) * 16;

    // ---- stage x^T tile: 256 c-rows x 16 pixels ----
    {
        const float* xp = x + (size_t)b * C * N + n0;
        const int cr = tid >> 2;         // 0..63
        const int f  = tid & 3;          // float4 within 16 px
#pragma unroll
        for (int p = 0; p < 4; ++p) {
            int c = p * 64 + cr;
            float4 v = *reinterpret_cast<const float4*>(xp + (size_t)c * N + f * 4);
            T[(f * 4 + 0) * TS + c] = f2bfs(v.x);
            T[(f * 4 + 1) * TS + c] = f2bfs(v.y);
            T[(f * 4 + 2) * TS + c] = f2bfs(v.z);
            T[(f * 4 + 3) * TS + c] = f2bfs(v.w);
        }
    }
    __syncthreads();

    // ---- gates (wave 0): logits via one MFMA, lane-local softmax ----
    if (wave == 0) {
        const float* wsrc = (col < 4) ? (Wsq + col * C) : (Wsk + (col & 3) * C);
        f32x4 ga = {};
#pragma unroll
        for (int k0 = 0; k0 < 256; k0 += 32) {
            float4 w0 = *reinterpret_cast<const float4*>(wsrc + k0 + quad * 8);
            float4 w1 = *reinterpret_cast<const float4*>(wsrc + k0 + quad * 8 + 4);
            short8 af = cvt8(w0, w1);
            short8 b0 = *reinterpret_cast<const short8*>(&T[col * TS + k0 + quad * 8]);
            ga = __builtin_amdgcn_mfma_f32_16x16x32_bf16(af, b0, ga, 0, 0, 0);
        }
        if (quad < 2) {
            const float* bsrc = (quad == 0) ? bsq : bsk;
            const float* gsrc = (quad == 0) ? gq : gk;
            int n = n0 + col;
            float a[4];
#pragma unroll
            for (int r = 0; r < 4; ++r)
                a[r] = ga[r] + bsrc[r] + gsrc[(size_t)b * 4 * N + (size_t)r * N + n];
            float mx = fmaxf(fmaxf(a[0], a[1]), fmaxf(a[2], a[3]));
            float e = 0.f;
#pragma unroll
            for (int r = 0; r < 4; ++r) e += __expf(a[r] - mx);
            float p0 = __expf(a[0] - mx) / e;
            if (quad == 0) { sq_lds[col] = p0; sqg[b * N + n] = p0; }
            else            sk_lds[col] = p0;
        }
    }
    __syncthreads();

    // ---- GEMM: 12 m-frags per wave, bf16 A direct b128 ----
    const short* Ws = reinterpret_cast<const short*>(Wb);
    const int mwbase = wave * 192;
    f32x4 acc[12] = {};
#pragma unroll
    for (int k0 = 0; k0 < 256; k0 += 32) {
        short8 b0 = *reinterpret_cast<const short8*>(&T[col * TS + k0 + quad * 8]);
#pragma unroll
        for (int i = 0; i < 12; ++i) {
            int m = mwbase + i * 16;
            const short* wr = Ws + (size_t)(m >> 8) * 65536
                              + (size_t)((m & 255) + col) * 256 + k0 + quad * 8;
            short8 af = *reinterpret_cast<const short8*>(wr);
            acc[i] = __builtin_amdgcn_mfma_f32_16x16x32_bf16(af, b0, acc[i], 0, 0, 0);
        }
    }
    // epilogue
    const int n = n0 + col;
#pragma unroll
    for (int i = 0; i < 12; ++i) {
        int m = mwbase + i * 16;
        int mat = m >> 8;
        int cr  = (m & 255) + quad * 4;
        const float* bb = (mat == 0) ? bq : (mat == 1) ? bk : bv;
        float bias[4];
#pragma unroll
        for (int r = 0; r < 4; ++r) bias[r] = bb[cr + r];
        if (mat < 2) {
            float g = (mat == 0) ? sq_lds[col] * SCALE : sk_lds[col];
            short* op = reinterpret_cast<short*>((mat == 0) ? qo : ko) + (size_t)b * N * C;
            sh4 pack;
#pragma unroll
            for (int r = 0; r < 4; ++r) pack[r] = f2bfs((acc[i][r] + bias[r]) * g);
            *reinterpret_cast<sh4*>(op + (size_t)n * C + cr) = pack;
        } else {
            bf16* op = vo + (size_t)b * C * N;
#pragma unroll
            for (int r = 0; r < 4; ++r)
                op[(size_t)(cr + r) * N + n] = __float2bfloat16(acc[i][r] + bias[r]);
        }
    }
}

// ---------------------------------------------------------------------------
// K2: attention + gated mix. 512 blocks = (b, head, 128-query tile),
// 2 blocks/CU. All 4 waves share one head's K/V stream (L1 reuse); wave =
// 32 queries with 2 Q-frags (1:2 K-load:MFMA). P per-wave LDS (stride 72).
// Writes gated rows to gt [B][N][C] pixel-major.
// ---------------------------------------------------------------------------
__global__ __launch_bounds__(256) void k_attn5(
    const bf16* __restrict__ qo, const bf16* __restrict__ ko,
    const bf16* __restrict__ vo, const float* __restrict__ sqg,
    bf16* __restrict__ gt)
{
    __shared__ short P_lds[4][32 * 72];   // 36.9 KB

    const int tid  = threadIdx.x;
    const int wave = tid >> 6;
    const int lane = tid & 63;
    const int col  = lane & 15;
    const int quad = lane >> 4;

    const int b = blockIdx.x >> 6;
    const int h = (blockIdx.x >> 3) & 7;
    const int qbase = (blockIdx.x & 7) * 128 + wave * 32;

    const short* kp = reinterpret_cast<const short*>(ko) + (size_t)b * N * C + h * HD + quad * 8;
    const short* vp = reinterpret_cast<const short*>(vo) + (size_t)b * C * N + (size_t)h * HD * N;

    short8 qf[2];
    {
        const short* qp = reinterpret_cast<const short*>(qo) + (size_t)b * N * C + h * HD + quad * 8;
#pragma unroll
        for (int g = 0; g < 2; ++g)
            qf[g] = *reinterpret_cast<const short8*>(qp + (size_t)(qbase + g * 16 + col) * C);
    }

    float l[2] = {};
    f32x4 oac[2][2] = {};   // [g][dh]
    short* P = P_lds[wave];

    short8 kf[4];
#pragma unroll
    for (int c = 0; c < 4; ++c)
        kf[c] = *reinterpret_cast<const short8*>(kp + (size_t)(c * 16 + col) * C);

    for (int kb = 0; kb < N; kb += 64) {
        short8 vf[2][2];
#pragma unroll
        for (int kg = 0; kg < 2; ++kg)
#pragma unroll
            for (int dh = 0; dh < 2; ++dh)
                vf[kg][dh] = *reinterpret_cast<const short8*>(vp + (size_t)(dh * 16 + col) * N + kb + kg * 32 + quad * 8);

#pragma unroll
        for (int g = 0; g < 2; ++g) {
            float s[16];
#pragma unroll
            for (int c = 0; c < 4; ++c) {
                f32x4 acc = {};
                acc = __builtin_amdgcn_mfma_f32_16x16x32_bf16(kf[c], qf[g], acc, 0, 0, 0);
#pragma unroll
                for (int r = 0; r < 4; ++r) s[c * 4 + r] = acc[r];
            }
            float p[16], lloc = 0.f;
#pragma unroll
            for (int i = 0; i < 16; ++i) { p[i] = __expf(s[i]); lloc += p[i]; }
            lloc += __shfl_xor(lloc, 16, 64);
            lloc += __shfl_xor(lloc, 32, 64);
            l[g] += lloc;
#pragma unroll
            for (int c = 0; c < 4; ++c) {
                sh4 pk;
#pragma unroll
                for (int r = 0; r < 4; ++r) pk[r] = f2bfs(p[c * 4 + r]);
                *reinterpret_cast<sh4*>(&P[(g * 16 + col) * 72 + c * 16 + quad * 4]) = pk;
            }
        }

        const int kn = (kb + 64) & (N - 1);
#pragma unroll
        for (int c = 0; c < 4; ++c)
            kf[c] = *reinterpret_cast<const short8*>(kp + (size_t)(kn + c * 16 + col) * C);

#pragma unroll
        for (int kg = 0; kg < 2; ++kg) {
#pragma unroll
            for (int g = 0; g < 2; ++g) {
                short8 pf = *reinterpret_cast<const short8*>(&P[(g * 16 + col) * 72 + kg * 32 + quad * 8]);
#pragma unroll
                for (int dh = 0; dh < 2; ++dh)
                    oac[g][dh] = __builtin_amdgcn_mfma_f32_16x16x32_bf16(vf[kg][dh], pf, oac[g][dh], 0, 0, 0);
            }
        }
    }

    // epilogue: gated mix, pixel-major packed stores
#pragma unroll
    for (int g = 0; g < 2; ++g) {
        const int q = qbase + g * 16 + col;
        const float invl = 1.f / l[g];
        const float sqv  = sqg[b * N + q];
        const float hv   = 1.f - sqv;
        short* gp = reinterpret_cast<short*>(gt) + ((size_t)b * N + q) * C + h * HD + quad * 4;
#pragma unroll
        for (int dh = 0; dh < 2; ++dh) {
            sh4 pack;
#pragma unroll
            for (int r = 0; r < 4; ++r) {
                int d = dh * 16 + quad * 4 + r;
                float vb = bf2f(*reinterpret_cast<const bf16*>(vp + (size_t)d * N + q));
                pack[r] = f2bfs(sqv * (oac[g][dh][r] * invl) + hv * vb);
            }
            *reinterpret_cast<sh4*>(gp + dh * 16) = pack;
        }
    }
}

// ---------------------------------------------------------------------------
// K3: projection MFMA GEMM (R6-proven). grid (4, 32, 8) = 1024 blocks.
// out = Wp @ g + bp, f32 [B][C][N].
// ---------------------------------------------------------------------------
__global__ __launch_bounds__(256) void k_projm2(
    const bf16* __restrict__ gt, const bf16* __restrict__ Wpb,
    const float* __restrict__ bp, float* __restrict__ out)
{
    const int tid  = threadIdx.x;
    const int wave = tid >> 6, lane = tid & 63;
    const int col  = lane & 15, quad = lane >> 4;
    const int mrow = blockIdx.x * 64;
    const int b    = blockIdx.z;
    const int n0   = blockIdx.y * 32;

    const short* Wm = reinterpret_cast<const short*>(Wpb);
    const short* gp = reinterpret_cast<const short*>(gt) + (size_t)b * N * C;
    const int m16 = mrow + wave * 16;

    f32x4 acc[2] = {};
#pragma unroll
    for (int k0 = 0; k0 < 256; k0 += 32) {
        short8 af = *reinterpret_cast<const short8*>(Wm + (size_t)(m16 + col) * 256 + k0 + quad * 8);
#pragma unroll
        for (int cf = 0; cf < 2; ++cf) {
            short8 bfr = *reinterpret_cast<const short8*>(gp + (size_t)(n0 + cf * 16 + col) * C + k0 + quad * 8);
            acc[cf] = __builtin_amdgcn_mfma_f32_16x16x32_bf16(af, bfr, acc[cf], 0, 0, 0);
        }
    }

    float bias[4];
#pragma unroll
    for (int r = 0; r < 4; ++r) bias[r] = bp[m16 + quad * 4 + r];
    float* op = out + (size_t)b * C * N;
#pragma unroll
    for (int cf = 0; cf < 2; ++cf) {
        int n = n0 + cf * 16 + col;
#pragma unroll
        for (int r = 0; r < 4; ++r) {
            int c = m16 + quad * 4 + r;
            op[(size_t)c * N + n] = acc[cf][r] + bias[r];
        }
    }
}

// ---------------------------------------------------------------------------
// Workspace (bytes):
//   [0, 32K)        sqg f32 [8][1024]
//   [32K, 544K)     Wb bf16 [4][256][256]  (q,k,v,p)
//   [544K, +4M)     qo bf16 [8][1024][256] (pixel-major, sq*SCALE folded)
//   +4M             ko bf16 [8][1024][256] (pixel-major, sk folded)
//   +4M             vo bf16 [8][256][1024] (d-major)
//   +4M             gt bf16 [8][1024][256] (gated rows, pixel-major)
// ---------------------------------------------------------------------------
extern "C" void kernel_launch(void* const* d_in, const int* in_sizes, int n_in,
                              void* d_out, int out_size, void* d_ws, size_t ws_size,
                              hipStream_t stream)
{
    const float* x   = (const float*)d_in[0];
    const float* gq  = (const float*)d_in[1];
    const float* gk  = (const float*)d_in[2];
    const float* Wsq = (const float*)d_in[3];
    const float* bsq = (const float*)d_in[4];
    const float* Wsk = (const float*)d_in[5];
    const float* bsk = (const float*)d_in[6];
    const float* Wq  = (const float*)d_in[7];
    const float* bq  = (const float*)d_in[8];
    const float* Wk  = (const float*)d_in[9];
    const float* bk  = (const float*)d_in[10];
    const float* Wv  = (const float*)d_in[11];
    const float* bv  = (const float*)d_in[12];
    const float* Wp  = (const float*)d_in[13];
    const float* bp  = (const float*)d_in[14];

    char* ws = (char*)d_ws;
    float* sqg = (float*)ws;
    bf16* Wb   = (bf16*)(ws + 32768);
    bf16* qo   = (bf16*)(ws + 32768 + 524288);
    bf16* ko   = qo + (size_t)Bn * N * C;
    bf16* vo   = ko + (size_t)Bn * N * C;
    bf16* gt   = vo + (size_t)Bn * C * N;
    float* out = (float*)d_out;

    k_prep<<<16, 256, 0, stream>>>(Wq, Wk, Wv, Wp, Wb);
    k_fused3<<<512, 256, 0, stream>>>(x, gq, gk, Wsq, bsq, Wsk, bsk,
                                      Wb, bq, bk, bv, qo, ko, vo, sqg);
    k_attn5<<<512, 256, 0, stream>>>(qo, ko, vo, sqg, gt);
    k_projm2<<<dim3(4, 32, 8), 256, 0, stream>>>(gt, Wb + 3 * 65536, bp, out);
}

// Round 16
// 153.347 us; speedup vs baseline: 1.1316x; 1.0835x over previous
//
#include <hip/hip_runtime.h>
#include <hip/hip_bf16.h>

typedef __hip_bfloat16 bf16;
typedef __attribute__((ext_vector_type(8))) short short8;
typedef __attribute__((ext_vector_type(4))) short sh4;
typedef __attribute__((ext_vector_type(4))) float f32x4;

static __device__ __forceinline__ float bf2f(bf16 h) { return __bfloat162float(h); }
static __device__ __forceinline__ short f2bfs(float f) {
    bf16 h = __float2bfloat16(f);
    return *reinterpret_cast<short*>(&h);
}
static __device__ __forceinline__ short8 cvt8(float4 a, float4 b) {
    short8 o;
    o[0] = f2bfs(a.x); o[1] = f2bfs(a.y); o[2] = f2bfs(a.z); o[3] = f2bfs(a.w);
    o[4] = f2bfs(b.x); o[5] = f2bfs(b.y); o[6] = f2bfs(b.z); o[7] = f2bfs(b.w);
    return o;
}

constexpr int Bn = 8;
constexpr int C  = 256;
constexpr int N  = 1024;     // H*W
constexpr int NH = 8;
constexpr int HD = 32;
constexpr int TS = 264;      // LDS tile stride (shorts)
constexpr float SCALE = 0.17677669529663687f;  // 1/sqrt(32)

// ---------------------------------------------------------------------------
// K0: convert Wq|Wk|Wv|Wp f32 -> Wb bf16 [4][256][256]. 16 blocks.
// ---------------------------------------------------------------------------
__global__ __launch_bounds__(256) void k_prep(
    const float* __restrict__ Wq, const float* __restrict__ Wk,
    const float* __restrict__ Wv, const float* __restrict__ Wp,
    bf16* __restrict__ Wb)
{
    const int tid = threadIdx.x;
    const int mat = blockIdx.x >> 2, seg = blockIdx.x & 3;
    const float* src = (mat == 0) ? Wq : (mat == 1) ? Wk : (mat == 2) ? Wv : Wp;
    short* dst = reinterpret_cast<short*>(Wb) + (size_t)mat * 256 * 256;
#pragma unroll
    for (int i = 0; i < 16; ++i) {
        int f4 = seg * 4096 + i * 256 + tid;
        float4 v = reinterpret_cast<const float4*>(src)[f4];
        sh4 o;
        o[0] = f2bfs(v.x); o[1] = f2bfs(v.y); o[2] = f2bfs(v.z); o[3] = f2bfs(v.w);
        *reinterpret_cast<sh4*>(dst + (size_t)f4 * 4) = o;
    }
}

// ---------------------------------------------------------------------------
// K1: fused transpose + gates + q/k/v GEMM. 512 blocks = (b, 32-px tile,
// m-half) -> 2 blocks/CU AND 1:2 A-load:MFMA (each A-frag feeds 2 B-frags).
// Per wave: 6 m-frags x 2 n-frags over its 384-row M half.
// ---------------------------------------------------------------------------
__global__ __launch_bounds__(256) void k_fused4(
    const float* __restrict__ x, const float* __restrict__ gq, const float* __restrict__ gk,
    const float* __restrict__ Wsq, const float* __restrict__ bsq,
    const float* __restrict__ Wsk, const float* __restrict__ bsk,
    const bf16* __restrict__ Wb,
    const float* __restrict__ bq, const float* __restrict__ bk, const float* __restrict__ bv,
    bf16* __restrict__ qo, bf16* __restrict__ ko, bf16* __restrict__ vo,
    float* __restrict__ sqg)
{
    __shared__ short T[32 * TS];     // [pixel][c], 16.9 KB
    __shared__ float sq_lds[32];
    __shared__ float sk_lds[32];

    const int tid  = threadIdx.x;
    const int wave = tid >> 6;
    const int lane = tid & 63;
    const int col  = lane & 15;
    const int quad = lane >> 4;

    const int b     = blockIdx.x >> 6;
    const int rest  = blockIdx.x & 63;
    const int n0    = (rest >> 1) * 32;
    const int mhalf = rest & 1;

    // ---- stage x^T tile: 256 c-rows x 32 pixels (R9-verified) ----
    {
        const float* xp = x + (size_t)b * C * N + n0;
        const int row = tid >> 3;        // c within pass
        const int f   = tid & 7;         // float4 within 32 pixels
#pragma unroll
        for (int p = 0; p < 8; ++p) {
            int c = p * 32 + row;
            float4 v = *reinterpret_cast<const float4*>(xp + (size_t)c * N + f * 4);
            T[(f * 4 + 0) * TS + c] = f2bfs(v.x);
            T[(f * 4 + 1) * TS + c] = f2bfs(v.y);
            T[(f * 4 + 2) * TS + c] = f2bfs(v.z);
            T[(f * 4 + 3) * TS + c] = f2bfs(v.w);
        }
    }
    __syncthreads();

    // ---- gates (wave 0 only, R9-verified): MFMA pair + lane softmax ----
    if (wave == 0) {
        const float* wsrc = (col < 4) ? (Wsq + col * C) : (Wsk + (col & 3) * C);
        f32x4 ga[2] = {};
#pragma unroll
        for (int k0 = 0; k0 < 256; k0 += 32) {
            float4 w0 = *reinterpret_cast<const float4*>(wsrc + k0 + quad * 8);
            float4 w1 = *reinterpret_cast<const float4*>(wsrc + k0 + quad * 8 + 4);
            short8 af = cvt8(w0, w1);
            short8 b0 = *reinterpret_cast<const short8*>(&T[col * TS + k0 + quad * 8]);
            short8 b1 = *reinterpret_cast<const short8*>(&T[(16 + col) * TS + k0 + quad * 8]);
            ga[0] = __builtin_amdgcn_mfma_f32_16x16x32_bf16(af, b0, ga[0], 0, 0, 0);
            ga[1] = __builtin_amdgcn_mfma_f32_16x16x32_bf16(af, b1, ga[1], 0, 0, 0);
        }
        if (quad < 2) {
            const float* bsrc = (quad == 0) ? bsq : bsk;
            const float* gsrc = (quad == 0) ? gq : gk;
#pragma unroll
            for (int cf = 0; cf < 2; ++cf) {
                int n = n0 + cf * 16 + col;
                float a[4];
#pragma unroll
                for (int r = 0; r < 4; ++r)
                    a[r] = ga[cf][r] + bsrc[r] + gsrc[(size_t)b * 4 * N + (size_t)r * N + n];
                float mx = fmaxf(fmaxf(a[0], a[1]), fmaxf(a[2], a[3]));
                float e = 0.f;
#pragma unroll
                for (int r = 0; r < 4; ++r) e += __expf(a[r] - mx);
                float p0 = __expf(a[0] - mx) / e;
                if (quad == 0) {
                    sq_lds[cf * 16 + col] = p0;
                    if (mhalf == 0) sqg[b * N + n] = p0;
                } else {
                    sk_lds[cf * 16 + col] = p0;
                }
            }
        }
    }
    __syncthreads();

    // ---- GEMM: this block's 384-row M half; 6 A-frags x 2 B-frags/wave ----
    const short* Ws = reinterpret_cast<const short*>(Wb);
    const int mbase = mhalf * 384 + wave * 96;
    f32x4 acc[6][2] = {};
#pragma unroll
    for (int k0 = 0; k0 < 256; k0 += 32) {
        short8 b0 = *reinterpret_cast<const short8*>(&T[col * TS + k0 + quad * 8]);
        short8 b1 = *reinterpret_cast<const short8*>(&T[(16 + col) * TS + k0 + quad * 8]);
#pragma unroll
        for (int i = 0; i < 6; ++i) {
            int m = mbase + i * 16;
            const short* wr = Ws + (size_t)(m >> 8) * 65536
                              + (size_t)((m & 255) + col) * 256 + k0 + quad * 8;
            short8 af = *reinterpret_cast<const short8*>(wr);
            acc[i][0] = __builtin_amdgcn_mfma_f32_16x16x32_bf16(af, b0, acc[i][0], 0, 0, 0);
            acc[i][1] = __builtin_amdgcn_mfma_f32_16x16x32_bf16(af, b1, acc[i][1], 0, 0, 0);
        }
    }
    // epilogue
#pragma unroll
    for (int i = 0; i < 6; ++i) {
        int m = mbase + i * 16;
        int mat = m >> 8;
        int cr  = (m & 255) + quad * 4;
        const float* bb = (mat == 0) ? bq : (mat == 1) ? bk : bv;
        float bias[4];
#pragma unroll
        for (int r = 0; r < 4; ++r) bias[r] = bb[cr + r];
        if (mat < 2) {
            short* op = reinterpret_cast<short*>((mat == 0) ? qo : ko) + (size_t)b * N * C;
#pragma unroll
            for (int cf = 0; cf < 2; ++cf) {
                int n = n0 + cf * 16 + col;
                float g = (mat == 0) ? sq_lds[cf * 16 + col] * SCALE
                                     : sk_lds[cf * 16 + col];
                sh4 pack;
#pragma unroll
                for (int r = 0; r < 4; ++r) pack[r] = f2bfs((acc[i][cf][r] + bias[r]) * g);
                *reinterpret_cast<sh4*>(op + (size_t)n * C + cr) = pack;
            }
        } else {
            bf16* op = vo + (size_t)b * C * N;
#pragma unroll
            for (int cf = 0; cf < 2; ++cf) {
                int n = n0 + cf * 16 + col;
#pragma unroll
                for (int r = 0; r < 4; ++r)
                    op[(size_t)(cr + r) * N + n] = __float2bfloat16(acc[i][cf][r] + bias[r]);
            }
        }
    }
}

// ---------------------------------------------------------------------------
// K2: attention + gated mix (R12/R15-verified, unchanged). 512 blocks =
// (b, head, 128-query tile), 2 blocks/CU; wave = 32 q with 2 Q-frags.
// ---------------------------------------------------------------------------
__global__ __launch_bounds__(256) void k_attn5(
    const bf16* __restrict__ qo, const bf16* __restrict__ ko,
    const bf16* __restrict__ vo, const float* __restrict__ sqg,
    bf16* __restrict__ gt)
{
    __shared__ short P_lds[4][32 * 72];   // 36.9 KB

    const int tid  = threadIdx.x;
    const int wave = tid >> 6;
    const int lane = tid & 63;
    const int col  = lane & 15;
    const int quad = lane >> 4;

    const int b = blockIdx.x >> 6;
    const int h = (blockIdx.x >> 3) & 7;
    const int qbase = (blockIdx.x & 7) * 128 + wave * 32;

    const short* kp = reinterpret_cast<const short*>(ko) + (size_t)b * N * C + h * HD + quad * 8;
    const short* vp = reinterpret_cast<const short*>(vo) + (size_t)b * C * N + (size_t)h * HD * N;

    short8 qf[2];
    {
        const short* qp = reinterpret_cast<const short*>(qo) + (size_t)b * N * C + h * HD + quad * 8;
#pragma unroll
        for (int g = 0; g < 2; ++g)
            qf[g] = *reinterpret_cast<const short8*>(qp + (size_t)(qbase + g * 16 + col) * C);
    }

    float l[2] = {};
    f32x4 oac[2][2] = {};   // [g][dh]
    short* P = P_lds[wave];

    short8 kf[4];
#pragma unroll
    for (int c = 0; c < 4; ++c)
        kf[c] = *reinterpret_cast<const short8*>(kp + (size_t)(c * 16 + col) * C);

    for (int kb = 0; kb < N; kb += 64) {
        short8 vf[2][2];
#pragma unroll
        for (int kg = 0; kg < 2; ++kg)
#pragma unroll
            for (int dh = 0; dh < 2; ++dh)
                vf[kg][dh] = *reinterpret_cast<const short8*>(vp + (size_t)(dh * 16 + col) * N + kb + kg * 32 + quad * 8);

#pragma unroll
        for (int g = 0; g < 2; ++g) {
            float s[16];
#pragma unroll
            for (int c = 0; c < 4; ++c) {
                f32x4 acc = {};
                acc = __builtin_amdgcn_mfma_f32_16x16x32_bf16(kf[c], qf[g], acc, 0, 0, 0);
#pragma unroll
                for (int r = 0; r < 4; ++r) s[c * 4 + r] = acc[r];
            }
            float p[16], lloc = 0.f;
#pragma unroll
            for (int i = 0; i < 16; ++i) { p[i] = __expf(s[i]); lloc += p[i]; }
            lloc += __shfl_xor(lloc, 16, 64);
            lloc += __shfl_xor(lloc, 32, 64);
            l[g] += lloc;
#pragma unroll
            for (int c = 0; c < 4; ++c) {
                sh4 pk;
#pragma unroll
                for (int r = 0; r < 4; ++r) pk[r] = f2bfs(p[c * 4 + r]);
                *reinterpret_cast<sh4*>(&P[(g * 16 + col) * 72 + c * 16 + quad * 4]) = pk;
            }
        }

        const int kn = (kb + 64) & (N - 1);
#pragma unroll
        for (int c = 0; c < 4; ++c)
            kf[c] = *reinterpret_cast<const short8*>(kp + (size_t)(kn + c * 16 + col) * C);

#pragma unroll
        for (int kg = 0; kg < 2; ++kg) {
#pragma unroll
            for (int g = 0; g < 2; ++g) {
                short8 pf = *reinterpret_cast<const short8*>(&P[(g * 16 + col) * 72 + kg * 32 + quad * 8]);
#pragma unroll
                for (int dh = 0; dh < 2; ++dh)
                    oac[g][dh] = __builtin_amdgcn_mfma_f32_16x16x32_bf16(vf[kg][dh], pf, oac[g][dh], 0, 0, 0);
            }
        }
    }

    // epilogue: gated mix, pixel-major packed stores
#pragma unroll
    for (int g = 0; g < 2; ++g) {
        const int q = qbase + g * 16 + col;
        const float invl = 1.f / l[g];
        const float sqv  = sqg[b * N + q];
        const float hv   = 1.f - sqv;
        short* gp = reinterpret_cast<short*>(gt) + ((size_t)b * N + q) * C + h * HD + quad * 4;
#pragma unroll
        for (int dh = 0; dh < 2; ++dh) {
            sh4 pack;
#pragma unroll
            for (int r = 0; r < 4; ++r) {
                int d = dh * 16 + quad * 4 + r;
                float vb = bf2f(*reinterpret_cast<const bf16*>(vp + (size_t)d * N + q));
                pack[r] = f2bfs(sqv * (oac[g][dh][r] * invl) + hv * vb);
            }
            *reinterpret_cast<sh4*>(gp + dh * 16) = pack;
        }
    }
}

// ---------------------------------------------------------------------------
// K3: projection MFMA GEMM (R6/R15-verified, unchanged). grid (4, 32, 8).
// ---------------------------------------------------------------------------
__global__ __launch_bounds__(256) void k_projm2(
    const bf16* __restrict__ gt, const bf16* __restrict__ Wpb,
    const float* __restrict__ bp, float* __restrict__ out)
{
    const int tid  = threadIdx.x;
    const int wave = tid >> 6, lane = tid & 63;
    const int col  = lane & 15, quad = lane >> 4;
    const int mrow = blockIdx.x * 64;
    const int b    = blockIdx.z;
    const int n0   = blockIdx.y * 32;

    const short* Wm = reinterpret_cast<const short*>(Wpb);
    const short* gp = reinterpret_cast<const short*>(gt) + (size_t)b * N * C;
    const int m16 = mrow + wave * 16;

    f32x4 acc[2] = {};
#pragma unroll
    for (int k0 = 0; k0 < 256; k0 += 32) {
        short8 af = *reinterpret_cast<const short8*>(Wm + (size_t)(m16 + col) * 256 + k0 + quad * 8);
#pragma unroll
        for (int cf = 0; cf < 2; ++cf) {
            short8 bfr = *reinterpret_cast<const short8*>(gp + (size_t)(n0 + cf * 16 + col) * C + k0 + quad * 8);
            acc[cf] = __builtin_amdgcn_mfma_f32_16x16x32_bf16(af, bfr, acc[cf], 0, 0, 0);
        }
    }

    float bias[4];
#pragma unroll
    for (int r = 0; r < 4; ++r) bias[r] = bp[m16 + quad * 4 + r];
    float* op = out + (size_t)b * C * N;
#pragma unroll
    for (int cf = 0; cf < 2; ++cf) {
        int n = n0 + cf * 16 + col;
#pragma unroll
        for (int r = 0; r < 4; ++r) {
            int c = m16 + quad * 4 + r;
            op[(size_t)c * N + n] = acc[cf][r] + bias[r];
        }
    }
}

// ---------------------------------------------------------------------------
// Workspace (bytes):
//   [0, 32K)        sqg f32 [8][1024]
//   [32K, 544K)     Wb bf16 [4][256][256]  (q,k,v,p)
//   [544K, +4M)     qo bf16 [8][1024][256] (pixel-major, sq*SCALE folded)
//   +4M             ko bf16 [8][1024][256] (pixel-major, sk folded)
//   +4M             vo bf16 [8][256][1024] (d-major)
//   +4M             gt bf16 [8][1024][256] (gated rows, pixel-major)
// ---------------------------------------------------------------------------
extern "C" void kernel_launch(void* const* d_in, const int* in_sizes, int n_in,
                              void* d_out, int out_size, void* d_ws, size_t ws_size,
                              hipStream_t stream)
{
    const float* x   = (const float*)d_in[0];
    const float* gq  = (const float*)d_in[1];
    const float* gk  = (const float*)d_in[2];
    const float* Wsq = (const float*)d_in[3];
    const float* bsq = (const float*)d_in[4];
    const float* Wsk = (const float*)d_in[5];
    const float* bsk = (const float*)d_in[6];
    const float* Wq  = (const float*)d_in[7];
    const float* bq  = (const float*)d_in[8];
    const float* Wk  = (const float*)d_in[9];
    const float* bk  = (const float*)d_in[10];
    const float* Wv  = (const float*)d_in[11];
    const float* bv  = (const float*)d_in[12];
    const float* Wp  = (const float*)d_in[13];
    const float* bp  = (const float*)d_in[14];

    char* ws = (char*)d_ws;
    float* sqg = (float*)ws;
    bf16* Wb   = (bf16*)(ws + 32768);
    bf16* qo   = (bf16*)(ws + 32768 + 524288);
    bf16* ko   = qo + (size_t)Bn * N * C;
    bf16* vo   = ko + (size_t)Bn * N * C;
    bf16* gt   = vo + (size_t)Bn * C * N;
    float* out = (float*)d_out;

    k_prep<<<16, 256, 0, stream>>>(Wq, Wk, Wv, Wp, Wb);
    k_fused4<<<512, 256, 0, stream>>>(x, gq, gk, Wsq, bsq, Wsk, bsk,
                                      Wb, bq, bk, bv, qo, ko, vo, sqg);
    k_attn5<<<512, 256, 0, stream>>>(qo, ko, vo, sqg, gt);
    k_projm2<<<dim3(4, 32, 8), 256, 0, stream>>>(gt, Wb + 3 * 65536, bp, out);
}

// Round 17
// 148.958 us; speedup vs baseline: 1.1650x; 1.0295x over previous
//
#include <hip/hip_runtime.h>
#include <hip/hip_bf16.h>

typedef __hip_bfloat16 bf16;
typedef __attribute__((ext_vector_type(8))) short short8;
typedef __attribute__((ext_vector_type(4))) short sh4;
typedef __attribute__((ext_vector_type(4))) float f32x4;

static __device__ __forceinline__ float bf2f(bf16 h) { return __bfloat162float(h); }
static __device__ __forceinline__ short f2bfs(float f) {
    bf16 h = __float2bfloat16(f);
    return *reinterpret_cast<short*>(&h);
}
static __device__ __forceinline__ short8 cvt8(float4 a, float4 b) {
    short8 o;
    o[0] = f2bfs(a.x); o[1] = f2bfs(a.y); o[2] = f2bfs(a.z); o[3] = f2bfs(a.w);
    o[4] = f2bfs(b.x); o[5] = f2bfs(b.y); o[6] = f2bfs(b.z); o[7] = f2bfs(b.w);
    return o;
}

constexpr int Bn = 8;
constexpr int C  = 256;
constexpr int N  = 1024;     // H*W
constexpr int NH = 8;
constexpr int HD = 32;
constexpr int TS = 264;      // LDS tile stride (shorts)
constexpr float SCALE = 0.17677669529663687f;  // 1/sqrt(32)

// ---------------------------------------------------------------------------
// K0: convert Wq|Wk|Wv|Wp f32 -> Wb bf16 [4][256][256]. 16 blocks.
// ---------------------------------------------------------------------------
__global__ __launch_bounds__(256) void k_prep(
    const float* __restrict__ Wq, const float* __restrict__ Wk,
    const float* __restrict__ Wv, const float* __restrict__ Wp,
    bf16* __restrict__ Wb)
{
    const int tid = threadIdx.x;
    const int mat = blockIdx.x >> 2, seg = blockIdx.x & 3;
    const float* src = (mat == 0) ? Wq : (mat == 1) ? Wk : (mat == 2) ? Wv : Wp;
    short* dst = reinterpret_cast<short*>(Wb) + (size_t)mat * 256 * 256;
#pragma unroll
    for (int i = 0; i < 16; ++i) {
        int f4 = seg * 4096 + i * 256 + tid;
        float4 v = reinterpret_cast<const float4*>(src)[f4];
        sh4 o;
        o[0] = f2bfs(v.x); o[1] = f2bfs(v.y); o[2] = f2bfs(v.z); o[3] = f2bfs(v.w);
        *reinterpret_cast<sh4*>(dst + (size_t)f4 * 4) = o;
    }
}

// ---------------------------------------------------------------------------
// K1: fused transpose + gates + q/k/v GEMM. 512 blocks = (b, 64-px tile,
// m-quarter) -> 2 blocks/CU, 3 A-global-loads : 4 B-LDS : 12 MFMAs per
// wave per k-step (each A-frag feeds 4 B-frags).
// ---------------------------------------------------------------------------
__global__ __launch_bounds__(256) void k_fused5(
    const float* __restrict__ x, const float* __restrict__ gq, const float* __restrict__ gk,
    const float* __restrict__ Wsq, const float* __restrict__ bsq,
    const float* __restrict__ Wsk, const float* __restrict__ bsk,
    const bf16* __restrict__ Wb,
    const float* __restrict__ bq, const float* __restrict__ bk, const float* __restrict__ bv,
    bf16* __restrict__ qo, bf16* __restrict__ ko, bf16* __restrict__ vo,
    float* __restrict__ sqg)
{
    __shared__ short T[64 * TS];     // [pixel][c], 33.8 KB
    __shared__ float sq_lds[64];
    __shared__ float sk_lds[64];

    const int tid  = threadIdx.x;
    const int wave = tid >> 6;
    const int lane = tid & 63;
    const int col  = lane & 15;
    const int quad = lane >> 4;

    const int b    = blockIdx.x >> 6;
    const int rest = blockIdx.x & 63;
    const int n0   = (rest >> 2) * 64;   // 16 tiles of 64 px
    const int mq   = rest & 3;           // m-quarter (192 rows)

    // ---- stage x^T tile: 256 c-rows x 64 pixels ----
    {
        const float* xp = x + (size_t)b * C * N + n0;
        const int row = tid >> 4;        // 0..15 (c within pass)
        const int f   = tid & 15;        // float4 within 64 pixels
#pragma unroll
        for (int p = 0; p < 16; ++p) {
            int c = p * 16 + row;
            float4 v = *reinterpret_cast<const float4*>(xp + (size_t)c * N + f * 4);
            T[(f * 4 + 0) * TS + c] = f2bfs(v.x);
            T[(f * 4 + 1) * TS + c] = f2bfs(v.y);
            T[(f * 4 + 2) * TS + c] = f2bfs(v.z);
            T[(f * 4 + 3) * TS + c] = f2bfs(v.w);
        }
    }
    __syncthreads();

    // ---- gates (wave 0 only): logits via MFMA over 4 B-frags ----
    if (wave == 0) {
        const float* wsrc = (col < 4) ? (Wsq + col * C) : (Wsk + (col & 3) * C);
        f32x4 ga[4] = {};
#pragma unroll
        for (int k0 = 0; k0 < 256; k0 += 32) {
            float4 w0 = *reinterpret_cast<const float4*>(wsrc + k0 + quad * 8);
            float4 w1 = *reinterpret_cast<const float4*>(wsrc + k0 + quad * 8 + 4);
            short8 af = cvt8(w0, w1);
#pragma unroll
            for (int cf = 0; cf < 4; ++cf) {
                short8 bfr = *reinterpret_cast<const short8*>(&T[(cf * 16 + col) * TS + k0 + quad * 8]);
                ga[cf] = __builtin_amdgcn_mfma_f32_16x16x32_bf16(af, bfr, ga[cf], 0, 0, 0);
            }
        }
        if (quad < 2) {
            const float* bsrc = (quad == 0) ? bsq : bsk;
            const float* gsrc = (quad == 0) ? gq : gk;
#pragma unroll
            for (int cf = 0; cf < 4; ++cf) {
                int n = n0 + cf * 16 + col;
                float a[4];
#pragma unroll
                for (int r = 0; r < 4; ++r)
                    a[r] = ga[cf][r] + bsrc[r] + gsrc[(size_t)b * 4 * N + (size_t)r * N + n];
                float mx = fmaxf(fmaxf(a[0], a[1]), fmaxf(a[2], a[3]));
                float e = 0.f;
#pragma unroll
                for (int r = 0; r < 4; ++r) e += __expf(a[r] - mx);
                float p0 = __expf(a[0] - mx) / e;
                if (quad == 0) {
                    sq_lds[cf * 16 + col] = p0;
                    if (mq == 0) sqg[b * N + n] = p0;
                } else {
                    sk_lds[cf * 16 + col] = p0;
                }
            }
        }
    }
    __syncthreads();

    // ---- GEMM: this block's 192-row M quarter; 3 A-frags x 4 B-frags ----
    const short* Ws = reinterpret_cast<const short*>(Wb);
    const int mbase = mq * 192 + wave * 48;
    f32x4 acc[3][4] = {};
#pragma unroll
    for (int k0 = 0; k0 < 256; k0 += 32) {
        short8 bfr[4];
#pragma unroll
        for (int cf = 0; cf < 4; ++cf)
            bfr[cf] = *reinterpret_cast<const short8*>(&T[(cf * 16 + col) * TS + k0 + quad * 8]);
#pragma unroll
        for (int i = 0; i < 3; ++i) {
            int m = mbase + i * 16;
            const short* wr = Ws + (size_t)(m >> 8) * 65536
                              + (size_t)((m & 255) + col) * 256 + k0 + quad * 8;
            short8 af = *reinterpret_cast<const short8*>(wr);
#pragma unroll
            for (int cf = 0; cf < 4; ++cf)
                acc[i][cf] = __builtin_amdgcn_mfma_f32_16x16x32_bf16(af, bfr[cf], acc[i][cf], 0, 0, 0);
        }
    }
    // epilogue (per-frag mat handles quarters spanning matrix boundaries)
#pragma unroll
    for (int i = 0; i < 3; ++i) {
        int m = mbase + i * 16;
        int mat = m >> 8;
        int cr  = (m & 255) + quad * 4;
        const float* bb = (mat == 0) ? bq : (mat == 1) ? bk : bv;
        float bias[4];
#pragma unroll
        for (int r = 0; r < 4; ++r) bias[r] = bb[cr + r];
        if (mat < 2) {
            short* op = reinterpret_cast<short*>((mat == 0) ? qo : ko) + (size_t)b * N * C;
#pragma unroll
            for (int cf = 0; cf < 4; ++cf) {
                int n = n0 + cf * 16 + col;
                float g = (mat == 0) ? sq_lds[cf * 16 + col] * SCALE
                                     : sk_lds[cf * 16 + col];
                sh4 pack;
#pragma unroll
                for (int r = 0; r < 4; ++r) pack[r] = f2bfs((acc[i][cf][r] + bias[r]) * g);
                *reinterpret_cast<sh4*>(op + (size_t)n * C + cr) = pack;
            }
        } else {
            bf16* op = vo + (size_t)b * C * N;
#pragma unroll
            for (int cf = 0; cf < 4; ++cf) {
                int n = n0 + cf * 16 + col;
#pragma unroll
                for (int r = 0; r < 4; ++r)
                    op[(size_t)(cr + r) * N + n] = __float2bfloat16(acc[i][cf][r] + bias[r]);
            }
        }
    }
}

// ---------------------------------------------------------------------------
// K2: attention + gated mix (R12/R16-verified, unchanged). 512 blocks =
// (b, head, 128-query tile), 2 blocks/CU; wave = 32 q with 2 Q-frags.
// ---------------------------------------------------------------------------
__global__ __launch_bounds__(256) void k_attn5(
    const bf16* __restrict__ qo, const bf16* __restrict__ ko,
    const bf16* __restrict__ vo, const float* __restrict__ sqg,
    bf16* __restrict__ gt)
{
    __shared__ short P_lds[4][32 * 72];   // 36.9 KB

    const int tid  = threadIdx.x;
    const int wave = tid >> 6;
    const int lane = tid & 63;
    const int col  = lane & 15;
    const int quad = lane >> 4;

    const int b = blockIdx.x >> 6;
    const int h = (blockIdx.x >> 3) & 7;
    const int qbase = (blockIdx.x & 7) * 128 + wave * 32;

    const short* kp = reinterpret_cast<const short*>(ko) + (size_t)b * N * C + h * HD + quad * 8;
    const short* vp = reinterpret_cast<const short*>(vo) + (size_t)b * C * N + (size_t)h * HD * N;

    short8 qf[2];
    {
        const short* qp = reinterpret_cast<const short*>(qo) + (size_t)b * N * C + h * HD + quad * 8;
#pragma unroll
        for (int g = 0; g < 2; ++g)
            qf[g] = *reinterpret_cast<const short8*>(qp + (size_t)(qbase + g * 16 + col) * C);
    }

    float l[2] = {};
    f32x4 oac[2][2] = {};   // [g][dh]
    short* P = P_lds[wave];

    short8 kf[4];
#pragma unroll
    for (int c = 0; c < 4; ++c)
        kf[c] = *reinterpret_cast<const short8*>(kp + (size_t)(c * 16 + col) * C);

    for (int kb = 0; kb < N; kb += 64) {
        short8 vf[2][2];
#pragma unroll
        for (int kg = 0; kg < 2; ++kg)
#pragma unroll
            for (int dh = 0; dh < 2; ++dh)
                vf[kg][dh] = *reinterpret_cast<const short8*>(vp + (size_t)(dh * 16 + col) * N + kb + kg * 32 + quad * 8);

#pragma unroll
        for (int g = 0; g < 2; ++g) {
            float s[16];
#pragma unroll
            for (int c = 0; c < 4; ++c) {
                f32x4 acc = {};
                acc = __builtin_amdgcn_mfma_f32_16x16x32_bf16(kf[c], qf[g], acc, 0, 0, 0);
#pragma unroll
                for (int r = 0; r < 4; ++r) s[c * 4 + r] = acc[r];
            }
            float p[16], lloc = 0.f;
#pragma unroll
            for (int i = 0; i < 16; ++i) { p[i] = __expf(s[i]); lloc += p[i]; }
            lloc += __shfl_xor(lloc, 16, 64);
            lloc += __shfl_xor(lloc, 32, 64);
            l[g] += lloc;
#pragma unroll
            for (int c = 0; c < 4; ++c) {
                sh4 pk;
#pragma unroll
                for (int r = 0; r < 4; ++r) pk[r] = f2bfs(p[c * 4 + r]);
                *reinterpret_cast<sh4*>(&P[(g * 16 + col) * 72 + c * 16 + quad * 4]) = pk;
            }
        }

        const int kn = (kb + 64) & (N - 1);
#pragma unroll
        for (int c = 0; c < 4; ++c)
            kf[c] = *reinterpret_cast<const short8*>(kp + (size_t)(kn + c * 16 + col) * C);

#pragma unroll
        for (int kg = 0; kg < 2; ++kg) {
#pragma unroll
            for (int g = 0; g < 2; ++g) {
                short8 pf = *reinterpret_cast<const short8*>(&P[(g * 16 + col) * 72 + kg * 32 + quad * 8]);
#pragma unroll
                for (int dh = 0; dh < 2; ++dh)
                    oac[g][dh] = __builtin_amdgcn_mfma_f32_16x16x32_bf16(vf[kg][dh], pf, oac[g][dh], 0, 0, 0);
            }
        }
    }

    // epilogue: gated mix, pixel-major packed stores
#pragma unroll
    for (int g = 0; g < 2; ++g) {
        const int q = qbase + g * 16 + col;
        const float invl = 1.f / l[g];
        const float sqv  = sqg[b * N + q];
        const float hv   = 1.f - sqv;
        short* gp = reinterpret_cast<short*>(gt) + ((size_t)b * N + q) * C + h * HD + quad * 4;
#pragma unroll
        for (int dh = 0; dh < 2; ++dh) {
            sh4 pack;
#pragma unroll
            for (int r = 0; r < 4; ++r) {
                int d = dh * 16 + quad * 4 + r;
                float vb = bf2f(*reinterpret_cast<const bf16*>(vp + (size_t)d * N + q));
                pack[r] = f2bfs(sqv * (oac[g][dh][r] * invl) + hv * vb);
            }
            *reinterpret_cast<sh4*>(gp + dh * 16) = pack;
        }
    }
}

// ---------------------------------------------------------------------------
// K3: projection MFMA GEMM, 2 m-frags x 2 n-frags per wave (1.0 loads/MFMA).
// grid (2, 32, 8) = 512 blocks = 2/CU; block = 128m x 32n.
// ---------------------------------------------------------------------------
__global__ __launch_bounds__(256) void k_projm3(
    const bf16* __restrict__ gt, const bf16* __restrict__ Wpb,
    const float* __restrict__ bp, float* __restrict__ out)
{
    const int tid  = threadIdx.x;
    const int wave = tid >> 6, lane = tid & 63;
    const int col  = lane & 15, quad = lane >> 4;
    const int mrow = blockIdx.x * 128 + wave * 32;   // wave owns 32 m rows
    const int b    = blockIdx.z;
    const int n0   = blockIdx.y * 32;

    const short* Wm = reinterpret_cast<const short*>(Wpb);
    const short* gp = reinterpret_cast<const short*>(gt) + (size_t)b * N * C;

    f32x4 acc[2][2] = {};   // [mfrag][nfrag]
#pragma unroll
    for (int k0 = 0; k0 < 256; k0 += 32) {
        short8 af[2];
#pragma unroll
        for (int mi = 0; mi < 2; ++mi)
            af[mi] = *reinterpret_cast<const short8*>(Wm + (size_t)(mrow + mi * 16 + col) * 256 + k0 + quad * 8);
        short8 bfr[2];
#pragma unroll
        for (int cf = 0; cf < 2; ++cf)
            bfr[cf] = *reinterpret_cast<const short8*>(gp + (size_t)(n0 + cf * 16 + col) * C + k0 + quad * 8);
#pragma unroll
        for (int mi = 0; mi < 2; ++mi)
#pragma unroll
            for (int cf = 0; cf < 2; ++cf)
                acc[mi][cf] = __builtin_amdgcn_mfma_f32_16x16x32_bf16(af[mi], bfr[cf], acc[mi][cf], 0, 0, 0);
    }

    float* op = out + (size_t)b * C * N;
#pragma unroll
    for (int mi = 0; mi < 2; ++mi) {
        int cr = mrow + mi * 16 + quad * 4;
        float bias[4];
#pragma unroll
        for (int r = 0; r < 4; ++r) bias[r] = bp[cr + r];
#pragma unroll
        for (int cf = 0; cf < 2; ++cf) {
            int n = n0 + cf * 16 + col;
#pragma unroll
            for (int r = 0; r < 4; ++r)
                op[(size_t)(cr + r) * N + n] = acc[mi][cf][r] + bias[r];
        }
    }
}

// ---------------------------------------------------------------------------
// Workspace (bytes):
//   [0, 32K)        sqg f32 [8][1024]
//   [32K, 544K)     Wb bf16 [4][256][256]  (q,k,v,p)
//   [544K, +4M)     qo bf16 [8][1024][256] (pixel-major, sq*SCALE folded)
//   +4M             ko bf16 [8][1024][256] (pixel-major, sk folded)
//   +4M             vo bf16 [8][256][1024] (d-major)
//   +4M             gt bf16 [8][1024][256] (gated rows, pixel-major)
// ---------------------------------------------------------------------------
extern "C" void kernel_launch(void* const* d_in, const int* in_sizes, int n_in,
                              void* d_out, int out_size, void* d_ws, size_t ws_size,
                              hipStream_t stream)
{
    const float* x   = (const float*)d_in[0];
    const float* gq  = (const float*)d_in[1];
    const float* gk  = (const float*)d_in[2];
    const float* Wsq = (const float*)d_in[3];
    const float* bsq = (const float*)d_in[4];
    const float* Wsk = (const float*)d_in[5];
    const float* bsk = (const float*)d_in[6];
    const float* Wq  = (const float*)d_in[7];
    const float* bq  = (const float*)d_in[8];
    const float* Wk  = (const float*)d_in[9];
    const float* bk  = (const float*)d_in[10];
    const float* Wv  = (const float*)d_in[11];
    const float* bv  = (const float*)d_in[12];
    const float* Wp  = (const float*)d_in[13];
    const float* bp  = (const float*)d_in[14];

    char* ws = (char*)d_ws;
    float* sqg = (float*)ws;
    bf16* Wb   = (bf16*)(ws + 32768);
    bf16* qo   = (bf16*)(ws + 32768 + 524288);
    bf16* ko   = qo + (size_t)Bn * N * C;
    bf16* vo   = ko + (size_t)Bn * N * C;
    bf16* gt   = vo + (size_t)Bn * C * N;
    float* out = (float*)d_out;

    k_prep<<<16, 256, 0, stream>>>(Wq, Wk, Wv, Wp, Wb);
    k_fused5<<<512, 256, 0, stream>>>(x, gq, gk, Wsq, bsq, Wsk, bsk,
                                      Wb, bq, bk, bv, qo, ko, vo, sqg);
    k_attn5<<<512, 256, 0, stream>>>(qo, ko, vo, sqg, gt);
    k_projm3<<<dim3(2, 32, 8), 256, 0, stream>>>(gt, Wb + 3 * 65536, bp, out);
}

// Round 18
// 138.722 us; speedup vs baseline: 1.2509x; 1.0738x over previous
//
#include <hip/hip_runtime.h>
#include <hip/hip_bf16.h>

typedef __hip_bfloat16 bf16;
typedef __attribute__((ext_vector_type(8))) short short8;
typedef __attribute__((ext_vector_type(4))) short sh4;
typedef __attribute__((ext_vector_type(4))) float f32x4;

static __device__ __forceinline__ float bf2f(bf16 h) { return __bfloat162float(h); }
static __device__ __forceinline__ short f2bfs(float f) {
    bf16 h = __float2bfloat16(f);
    return *reinterpret_cast<short*>(&h);
}
static __device__ __forceinline__ short8 cvt8(float4 a, float4 b) {
    short8 o;
    o[0] = f2bfs(a.x); o[1] = f2bfs(a.y); o[2] = f2bfs(a.z); o[3] = f2bfs(a.w);
    o[4] = f2bfs(b.x); o[5] = f2bfs(b.y); o[6] = f2bfs(b.z); o[7] = f2bfs(b.w);
    return o;
}

constexpr int Bn = 8;
constexpr int C  = 256;
constexpr int N  = 1024;     // H*W
constexpr int NH = 8;
constexpr int HD = 32;
constexpr int TS = 264;      // LDS tile stride (shorts)
constexpr float SCALE = 0.17677669529663687f;  // 1/sqrt(32)

// ---------------------------------------------------------------------------
// K0: convert Wq|Wk|Wv|Wp f32 -> Wb bf16 [4][256][256]. 16 blocks.
// ---------------------------------------------------------------------------
__global__ __launch_bounds__(256) void k_prep(
    const float* __restrict__ Wq, const float* __restrict__ Wk,
    const float* __restrict__ Wv, const float* __restrict__ Wp,
    bf16* __restrict__ Wb)
{
    const int tid = threadIdx.x;
    const int mat = blockIdx.x >> 2, seg = blockIdx.x & 3;
    const float* src = (mat == 0) ? Wq : (mat == 1) ? Wk : (mat == 2) ? Wv : Wp;
    short* dst = reinterpret_cast<short*>(Wb) + (size_t)mat * 256 * 256;
#pragma unroll
    for (int i = 0; i < 16; ++i) {
        int f4 = seg * 4096 + i * 256 + tid;
        float4 v = reinterpret_cast<const float4*>(src)[f4];
        sh4 o;
        o[0] = f2bfs(v.x); o[1] = f2bfs(v.y); o[2] = f2bfs(v.z); o[3] = f2bfs(v.w);
        *reinterpret_cast<sh4*>(dst + (size_t)f4 * 4) = o;
    }
}

// ---------------------------------------------------------------------------
// K1: fused transpose + gates + q/k/v GEMM (R17-verified, unchanged).
// 512 blocks = (b, 64-px tile, m-quarter), 3 A-loads : 12 MFMAs per k-step.
// ---------------------------------------------------------------------------
__global__ __launch_bounds__(256) void k_fused5(
    const float* __restrict__ x, const float* __restrict__ gq, const float* __restrict__ gk,
    const float* __restrict__ Wsq, const float* __restrict__ bsq,
    const float* __restrict__ Wsk, const float* __restrict__ bsk,
    const bf16* __restrict__ Wb,
    const float* __restrict__ bq, const float* __restrict__ bk, const float* __restrict__ bv,
    bf16* __restrict__ qo, bf16* __restrict__ ko, bf16* __restrict__ vo,
    float* __restrict__ sqg)
{
    __shared__ short T[64 * TS];     // [pixel][c], 33.8 KB
    __shared__ float sq_lds[64];
    __shared__ float sk_lds[64];

    const int tid  = threadIdx.x;
    const int wave = tid >> 6;
    const int lane = tid & 63;
    const int col  = lane & 15;
    const int quad = lane >> 4;

    const int b    = blockIdx.x >> 6;
    const int rest = blockIdx.x & 63;
    const int n0   = (rest >> 2) * 64;   // 16 tiles of 64 px
    const int mq   = rest & 3;           // m-quarter (192 rows)

    // ---- stage x^T tile: 256 c-rows x 64 pixels ----
    {
        const float* xp = x + (size_t)b * C * N + n0;
        const int row = tid >> 4;        // 0..15 (c within pass)
        const int f   = tid & 15;        // float4 within 64 pixels
#pragma unroll
        for (int p = 0; p < 16; ++p) {
            int c = p * 16 + row;
            float4 v = *reinterpret_cast<const float4*>(xp + (size_t)c * N + f * 4);
            T[(f * 4 + 0) * TS + c] = f2bfs(v.x);
            T[(f * 4 + 1) * TS + c] = f2bfs(v.y);
            T[(f * 4 + 2) * TS + c] = f2bfs(v.z);
            T[(f * 4 + 3) * TS + c] = f2bfs(v.w);
        }
    }
    __syncthreads();

    // ---- gates (wave 0 only): logits via MFMA over 4 B-frags ----
    if (wave == 0) {
        const float* wsrc = (col < 4) ? (Wsq + col * C) : (Wsk + (col & 3) * C);
        f32x4 ga[4] = {};
#pragma unroll
        for (int k0 = 0; k0 < 256; k0 += 32) {
            float4 w0 = *reinterpret_cast<const float4*>(wsrc + k0 + quad * 8);
            float4 w1 = *reinterpret_cast<const float4*>(wsrc + k0 + quad * 8 + 4);
            short8 af = cvt8(w0, w1);
#pragma unroll
            for (int cf = 0; cf < 4; ++cf) {
                short8 bfr = *reinterpret_cast<const short8*>(&T[(cf * 16 + col) * TS + k0 + quad * 8]);
                ga[cf] = __builtin_amdgcn_mfma_f32_16x16x32_bf16(af, bfr, ga[cf], 0, 0, 0);
            }
        }
        if (quad < 2) {
            const float* bsrc = (quad == 0) ? bsq : bsk;
            const float* gsrc = (quad == 0) ? gq : gk;
#pragma unroll
            for (int cf = 0; cf < 4; ++cf) {
                int n = n0 + cf * 16 + col;
                float a[4];
#pragma unroll
                for (int r = 0; r < 4; ++r)
                    a[r] = ga[cf][r] + bsrc[r] + gsrc[(size_t)b * 4 * N + (size_t)r * N + n];
                float mx = fmaxf(fmaxf(a[0], a[1]), fmaxf(a[2], a[3]));
                float e = 0.f;
#pragma unroll
                for (int r = 0; r < 4; ++r) e += __expf(a[r] - mx);
                float p0 = __expf(a[0] - mx) / e;
                if (quad == 0) {
                    sq_lds[cf * 16 + col] = p0;
                    if (mq == 0) sqg[b * N + n] = p0;
                } else {
                    sk_lds[cf * 16 + col] = p0;
                }
            }
        }
    }
    __syncthreads();

    // ---- GEMM: this block's 192-row M quarter; 3 A-frags x 4 B-frags ----
    const short* Ws = reinterpret_cast<const short*>(Wb);
    const int mbase = mq * 192 + wave * 48;
    f32x4 acc[3][4] = {};
#pragma unroll
    for (int k0 = 0; k0 < 256; k0 += 32) {
        short8 bfr[4];
#pragma unroll
        for (int cf = 0; cf < 4; ++cf)
            bfr[cf] = *reinterpret_cast<const short8*>(&T[(cf * 16 + col) * TS + k0 + quad * 8]);
#pragma unroll
        for (int i = 0; i < 3; ++i) {
            int m = mbase + i * 16;
            const short* wr = Ws + (size_t)(m >> 8) * 65536
                              + (size_t)((m & 255) + col) * 256 + k0 + quad * 8;
            short8 af = *reinterpret_cast<const short8*>(wr);
#pragma unroll
            for (int cf = 0; cf < 4; ++cf)
                acc[i][cf] = __builtin_amdgcn_mfma_f32_16x16x32_bf16(af, bfr[cf], acc[i][cf], 0, 0, 0);
        }
    }
    // epilogue (per-frag mat handles quarters spanning matrix boundaries)
#pragma unroll
    for (int i = 0; i < 3; ++i) {
        int m = mbase + i * 16;
        int mat = m >> 8;
        int cr  = (m & 255) + quad * 4;
        const float* bb = (mat == 0) ? bq : (mat == 1) ? bk : bv;
        float bias[4];
#pragma unroll
        for (int r = 0; r < 4; ++r) bias[r] = bb[cr + r];
        if (mat < 2) {
            short* op = reinterpret_cast<short*>((mat == 0) ? qo : ko) + (size_t)b * N * C;
#pragma unroll
            for (int cf = 0; cf < 4; ++cf) {
                int n = n0 + cf * 16 + col;
                float g = (mat == 0) ? sq_lds[cf * 16 + col] * SCALE
                                     : sk_lds[cf * 16 + col];
                sh4 pack;
#pragma unroll
                for (int r = 0; r < 4; ++r) pack[r] = f2bfs((acc[i][cf][r] + bias[r]) * g);
                *reinterpret_cast<sh4*>(op + (size_t)n * C + cr) = pack;
            }
        } else {
            bf16* op = vo + (size_t)b * C * N;
#pragma unroll
            for (int cf = 0; cf < 4; ++cf) {
                int n = n0 + cf * 16 + col;
#pragma unroll
                for (int r = 0; r < 4; ++r)
                    op[(size_t)(cr + r) * N + n] = __float2bfloat16(acc[i][cf][r] + bias[r]);
            }
        }
    }
}

// ---------------------------------------------------------------------------
// K2: attention + gated mix with cooperative double-buffered K/V LDS
// staging. 512 blocks = (b, head, 128-q tile), 2 blocks/CU. All 4 waves
// share the head's K/V; staging cuts global loads 8->2 instrs/wave/tile.
// K_lds [key][d] stride 40, V_lds [d][key] stride 72 (no transpose,
// <=2-way conflicts). One barrier per tile; next-tile globals issued
// before compute so latency overlaps MFMA.
// ---------------------------------------------------------------------------
__global__ __launch_bounds__(256) void k_attn6(
    const bf16* __restrict__ qo, const bf16* __restrict__ ko,
    const bf16* __restrict__ vo, const float* __restrict__ sqg,
    bf16* __restrict__ gt)
{
    __shared__ short P_lds[4][32 * 72];   // 36.9 KB
    __shared__ short K_lds[2][64 * 40];   // 10.2 KB
    __shared__ short V_lds[2][32 * 72];   //  9.2 KB  (total 56.3 KB)

    const int tid  = threadIdx.x;
    const int wave = tid >> 6;
    const int lane = tid & 63;
    const int col  = lane & 15;
    const int quad = lane >> 4;

    const int b = blockIdx.x >> 6;
    const int h = (blockIdx.x >> 3) & 7;
    const int qbase = (blockIdx.x & 7) * 128 + wave * 32;

    // staging indices (block-wide cooperative)
    const int skey = tid >> 2;          // 0..63
    const int sd   = (tid & 3) * 8;     // 0,8,16,24
    const int svd  = tid >> 3;          // 0..31
    const int svk  = (tid & 7) * 8;     // 0..56

    const short* kgp = reinterpret_cast<const short*>(ko) + (size_t)b * N * C + h * HD;
    const short* vgp = reinterpret_cast<const short*>(vo) + (size_t)b * C * N + (size_t)h * HD * N;
    const short* vp  = vgp;             // for epilogue gating reads

    short8 qf[2];
    {
        const short* qp = reinterpret_cast<const short*>(qo) + (size_t)b * N * C + h * HD + quad * 8;
#pragma unroll
        for (int g = 0; g < 2; ++g)
            qf[g] = *reinterpret_cast<const short8*>(qp + (size_t)(qbase + g * 16 + col) * C);
    }

    float l[2] = {};
    f32x4 oac[2][2] = {};   // [g][dh]
    short* P = P_lds[wave];

    // prologue: stage tile 0
    short8 kstage = *reinterpret_cast<const short8*>(kgp + (size_t)skey * C + sd);
    short8 vstage = *reinterpret_cast<const short8*>(vgp + (size_t)svd * N + svk);
    *reinterpret_cast<short8*>(&K_lds[0][skey * 40 + sd]) = kstage;
    *reinterpret_cast<short8*>(&V_lds[0][svd * 72 + svk]) = vstage;
    __syncthreads();

    for (int t = 0; t < 16; ++t) {
        const int tn = (t + 1) & 15;
        // issue next-tile global loads (latency overlapped with compute)
        kstage = *reinterpret_cast<const short8*>(kgp + (size_t)(tn * 64 + skey) * C + sd);
        vstage = *reinterpret_cast<const short8*>(vgp + (size_t)svd * N + tn * 64 + svk);

        const short* Kb = K_lds[t & 1];
        const short* Vb = V_lds[t & 1];

        short8 kf[4];
#pragma unroll
        for (int c = 0; c < 4; ++c)
            kf[c] = *reinterpret_cast<const short8*>(&Kb[(c * 16 + col) * 40 + quad * 8]);

#pragma unroll
        for (int g = 0; g < 2; ++g) {
            float s[16];
#pragma unroll
            for (int c = 0; c < 4; ++c) {
                f32x4 acc = {};
                acc = __builtin_amdgcn_mfma_f32_16x16x32_bf16(kf[c], qf[g], acc, 0, 0, 0);
#pragma unroll
                for (int r = 0; r < 4; ++r) s[c * 4 + r] = acc[r];
            }
            float p[16], lloc = 0.f;
#pragma unroll
            for (int i = 0; i < 16; ++i) { p[i] = __expf(s[i]); lloc += p[i]; }
            lloc += __shfl_xor(lloc, 16, 64);
            lloc += __shfl_xor(lloc, 32, 64);
            l[g] += lloc;
#pragma unroll
            for (int c = 0; c < 4; ++c) {
                sh4 pk;
#pragma unroll
                for (int r = 0; r < 4; ++r) pk[r] = f2bfs(p[c * 4 + r]);
                *reinterpret_cast<sh4*>(&P[(g * 16 + col) * 72 + c * 16 + quad * 4]) = pk;
            }
        }

#pragma unroll
        for (int kg = 0; kg < 2; ++kg) {
            short8 vf[2];
#pragma unroll
            for (int dh = 0; dh < 2; ++dh)
                vf[dh] = *reinterpret_cast<const short8*>(&Vb[(dh * 16 + col) * 72 + kg * 32 + quad * 8]);
#pragma unroll
            for (int g = 0; g < 2; ++g) {
                short8 pf = *reinterpret_cast<const short8*>(&P[(g * 16 + col) * 72 + kg * 32 + quad * 8]);
#pragma unroll
                for (int dh = 0; dh < 2; ++dh)
                    oac[g][dh] = __builtin_amdgcn_mfma_f32_16x16x32_bf16(vf[dh], pf, oac[g][dh], 0, 0, 0);
            }
        }

        // write next tile into the other buffer, then barrier
        *reinterpret_cast<short8*>(&K_lds[(t + 1) & 1][skey * 40 + sd]) = kstage;
        *reinterpret_cast<short8*>(&V_lds[(t + 1) & 1][svd * 72 + svk]) = vstage;
        __syncthreads();
    }

    // epilogue: gated mix, pixel-major packed stores
#pragma unroll
    for (int g = 0; g < 2; ++g) {
        const int q = qbase + g * 16 + col;
        const float invl = 1.f / l[g];
        const float sqv  = sqg[b * N + q];
        const float hv   = 1.f - sqv;
        short* gp = reinterpret_cast<short*>(gt) + ((size_t)b * N + q) * C + h * HD + quad * 4;
#pragma unroll
        for (int dh = 0; dh < 2; ++dh) {
            sh4 pack;
#pragma unroll
            for (int r = 0; r < 4; ++r) {
                int d = dh * 16 + quad * 4 + r;
                float vb = bf2f(*reinterpret_cast<const bf16*>(vp + (size_t)d * N + q));
                pack[r] = f2bfs(sqv * (oac[g][dh][r] * invl) + hv * vb);
            }
            *reinterpret_cast<sh4*>(gp + dh * 16) = pack;
        }
    }
}

// ---------------------------------------------------------------------------
// K3: projection MFMA GEMM (R17-verified, unchanged). 2m x 2n frags/wave.
// grid (2, 32, 8) = 512 blocks = 2/CU; block = 128m x 32n.
// ---------------------------------------------------------------------------
__global__ __launch_bounds__(256) void k_projm3(
    const bf16* __restrict__ gt, const bf16* __restrict__ Wpb,
    const float* __restrict__ bp, float* __restrict__ out)
{
    const int tid  = threadIdx.x;
    const int wave = tid >> 6, lane = tid & 63;
    const int col  = lane & 15, quad = lane >> 4;
    const int mrow = blockIdx.x * 128 + wave * 32;   // wave owns 32 m rows
    const int b    = blockIdx.z;
    const int n0   = blockIdx.y * 32;

    const short* Wm = reinterpret_cast<const short*>(Wpb);
    const short* gp = reinterpret_cast<const short*>(gt) + (size_t)b * N * C;

    f32x4 acc[2][2] = {};   // [mfrag][nfrag]
#pragma unroll
    for (int k0 = 0; k0 < 256; k0 += 32) {
        short8 af[2];
#pragma unroll
        for (int mi = 0; mi < 2; ++mi)
            af[mi] = *reinterpret_cast<const short8*>(Wm + (size_t)(mrow + mi * 16 + col) * 256 + k0 + quad * 8);
        short8 bfr[2];
#pragma unroll
        for (int cf = 0; cf < 2; ++cf)
            bfr[cf] = *reinterpret_cast<const short8*>(gp + (size_t)(n0 + cf * 16 + col) * C + k0 + quad * 8);
#pragma unroll
        for (int mi = 0; mi < 2; ++mi)
#pragma unroll
            for (int cf = 0; cf < 2; ++cf)
                acc[mi][cf] = __builtin_amdgcn_mfma_f32_16x16x32_bf16(af[mi], bfr[cf], acc[mi][cf], 0, 0, 0);
    }

    float* op = out + (size_t)b * C * N;
#pragma unroll
    for (int mi = 0; mi < 2; ++mi) {
        int cr = mrow + mi * 16 + quad * 4;
        float bias[4];
#pragma unroll
        for (int r = 0; r < 4; ++r) bias[r] = bp[cr + r];
#pragma unroll
        for (int cf = 0; cf < 2; ++cf) {
            int n = n0 + cf * 16 + col;
#pragma unroll
            for (int r = 0; r < 4; ++r)
                op[(size_t)(cr + r) * N + n] = acc[mi][cf][r] + bias[r];
        }
    }
}

// ---------------------------------------------------------------------------
// Workspace (bytes):
//   [0, 32K)        sqg f32 [8][1024]
//   [32K, 544K)     Wb bf16 [4][256][256]  (q,k,v,p)
//   [544K, +4M)     qo bf16 [8][1024][256] (pixel-major, sq*SCALE folded)
//   +4M             ko bf16 [8][1024][256] (pixel-major, sk folded)
//   +4M             vo bf16 [8][256][1024] (d-major)
//   +4M             gt bf16 [8][1024][256] (gated rows, pixel-major)
// ---------------------------------------------------------------------------
extern "C" void kernel_launch(void* const* d_in, const int* in_sizes, int n_in,
                              void* d_out, int out_size, void* d_ws, size_t ws_size,
                              hipStream_t stream)
{
    const float* x   = (const float*)d_in[0];
    const float* gq  = (const float*)d_in[1];
    const float* gk  = (const float*)d_in[2];
    const float* Wsq = (const float*)d_in[3];
    const float* bsq = (const float*)d_in[4];
    const float* Wsk = (const float*)d_in[5];
    const float* bsk = (const float*)d_in[6];
    const float* Wq  = (const float*)d_in[7];
    const float* bq  = (const float*)d_in[8];
    const float* Wk  = (const float*)d_in[9];
    const float* bk  = (const float*)d_in[10];
    const float* Wv  = (const float*)d_in[11];
    const float* bv  = (const float*)d_in[12];
    const float* Wp  = (const float*)d_in[13];
    const float* bp  = (const float*)d_in[14];

    char* ws = (char*)d_ws;
    float* sqg = (float*)ws;
    bf16* Wb   = (bf16*)(ws + 32768);
    bf16* qo   = (bf16*)(ws + 32768 + 524288);
    bf16* ko   = qo + (size_t)Bn * N * C;
    bf16* vo   = ko + (size_t)Bn * N * C;
    bf16* gt   = vo + (size_t)Bn * C * N;
    float* out = (float*)d_out;

    k_prep<<<16, 256, 0, stream>>>(Wq, Wk, Wv, Wp, Wb);
    k_fused5<<<512, 256, 0, stream>>>(x, gq, gk, Wsq, bsq, Wsk, bsk,
                                      Wb, bq, bk, bv, qo, ko, vo, sqg);
    k_attn6<<<512, 256, 0, stream>>>(qo, ko, vo, sqg, gt);
    k_projm3<<<dim3(2, 32, 8), 256, 0, stream>>>(gt, Wb + 3 * 65536, bp, out);
}

// Round 19
// 135.368 us; speedup vs baseline: 1.2819x; 1.0248x over previous
//
#include <hip/hip_runtime.h>
#include <hip/hip_bf16.h>

typedef __hip_bfloat16 bf16;
typedef __attribute__((ext_vector_type(8))) short short8;
typedef __attribute__((ext_vector_type(4))) short sh4;
typedef __attribute__((ext_vector_type(4))) float f32x4;

static __device__ __forceinline__ float bf2f(bf16 h) { return __bfloat162float(h); }
static __device__ __forceinline__ short f2bfs(float f) {
    bf16 h = __float2bfloat16(f);
    return *reinterpret_cast<short*>(&h);
}
static __device__ __forceinline__ short8 cvt8(float4 a, float4 b) {
    short8 o;
    o[0] = f2bfs(a.x); o[1] = f2bfs(a.y); o[2] = f2bfs(a.z); o[3] = f2bfs(a.w);
    o[4] = f2bfs(b.x); o[5] = f2bfs(b.y); o[6] = f2bfs(b.z); o[7] = f2bfs(b.w);
    return o;
}

constexpr int Bn = 8;
constexpr int C  = 256;
constexpr int N  = 1024;     // H*W
constexpr int NH = 8;
constexpr int HD = 32;
constexpr int TS = 264;      // LDS tile stride (shorts)
constexpr float SCALE = 0.17677669529663687f;  // 1/sqrt(32)

// ---------------------------------------------------------------------------
// K0: convert Wq|Wk|Wv|Wp f32 -> Wb bf16 [4][256][256]. 16 blocks.
// ---------------------------------------------------------------------------
__global__ __launch_bounds__(256) void k_prep(
    const float* __restrict__ Wq, const float* __restrict__ Wk,
    const float* __restrict__ Wv, const float* __restrict__ Wp,
    bf16* __restrict__ Wb)
{
    const int tid = threadIdx.x;
    const int mat = blockIdx.x >> 2, seg = blockIdx.x & 3;
    const float* src = (mat == 0) ? Wq : (mat == 1) ? Wk : (mat == 2) ? Wv : Wp;
    short* dst = reinterpret_cast<short*>(Wb) + (size_t)mat * 256 * 256;
#pragma unroll
    for (int i = 0; i < 16; ++i) {
        int f4 = seg * 4096 + i * 256 + tid;
        float4 v = reinterpret_cast<const float4*>(src)[f4];
        sh4 o;
        o[0] = f2bfs(v.x); o[1] = f2bfs(v.y); o[2] = f2bfs(v.z); o[3] = f2bfs(v.w);
        *reinterpret_cast<sh4*>(dst + (size_t)f4 * 4) = o;
    }
}

// ---------------------------------------------------------------------------
// K1: fused transpose + gates + q/k/v GEMM (R17/R18-verified, unchanged).
// 512 blocks = (b, 64-px tile, m-quarter), 3 A-loads : 12 MFMAs per k-step.
// ---------------------------------------------------------------------------
__global__ __launch_bounds__(256) void k_fused5(
    const float* __restrict__ x, const float* __restrict__ gq, const float* __restrict__ gk,
    const float* __restrict__ Wsq, const float* __restrict__ bsq,
    const float* __restrict__ Wsk, const float* __restrict__ bsk,
    const bf16* __restrict__ Wb,
    const float* __restrict__ bq, const float* __restrict__ bk, const float* __restrict__ bv,
    bf16* __restrict__ qo, bf16* __restrict__ ko, bf16* __restrict__ vo,
    float* __restrict__ sqg)
{
    __shared__ short T[64 * TS];     // [pixel][c], 33.8 KB
    __shared__ float sq_lds[64];
    __shared__ float sk_lds[64];

    const int tid  = threadIdx.x;
    const int wave = tid >> 6;
    const int lane = tid & 63;
    const int col  = lane & 15;
    const int quad = lane >> 4;

    const int b    = blockIdx.x >> 6;
    const int rest = blockIdx.x & 63;
    const int n0   = (rest >> 2) * 64;   // 16 tiles of 64 px
    const int mq   = rest & 3;           // m-quarter (192 rows)

    // ---- stage x^T tile: 256 c-rows x 64 pixels ----
    {
        const float* xp = x + (size_t)b * C * N + n0;
        const int row = tid >> 4;        // 0..15 (c within pass)
        const int f   = tid & 15;        // float4 within 64 pixels
#pragma unroll
        for (int p = 0; p < 16; ++p) {
            int c = p * 16 + row;
            float4 v = *reinterpret_cast<const float4*>(xp + (size_t)c * N + f * 4);
            T[(f * 4 + 0) * TS + c] = f2bfs(v.x);
            T[(f * 4 + 1) * TS + c] = f2bfs(v.y);
            T[(f * 4 + 2) * TS + c] = f2bfs(v.z);
            T[(f * 4 + 3) * TS + c] = f2bfs(v.w);
        }
    }
    __syncthreads();

    // ---- gates (wave 0 only): logits via MFMA over 4 B-frags ----
    if (wave == 0) {
        const float* wsrc = (col < 4) ? (Wsq + col * C) : (Wsk + (col & 3) * C);
        f32x4 ga[4] = {};
#pragma unroll
        for (int k0 = 0; k0 < 256; k0 += 32) {
            float4 w0 = *reinterpret_cast<const float4*>(wsrc + k0 + quad * 8);
            float4 w1 = *reinterpret_cast<const float4*>(wsrc + k0 + quad * 8 + 4);
            short8 af = cvt8(w0, w1);
#pragma unroll
            for (int cf = 0; cf < 4; ++cf) {
                short8 bfr = *reinterpret_cast<const short8*>(&T[(cf * 16 + col) * TS + k0 + quad * 8]);
                ga[cf] = __builtin_amdgcn_mfma_f32_16x16x32_bf16(af, bfr, ga[cf], 0, 0, 0);
            }
        }
        if (quad < 2) {
            const float* bsrc = (quad == 0) ? bsq : bsk;
            const float* gsrc = (quad == 0) ? gq : gk;
#pragma unroll
            for (int cf = 0; cf < 4; ++cf) {
                int n = n0 + cf * 16 + col;
                float a[4];
#pragma unroll
                for (int r = 0; r < 4; ++r)
                    a[r] = ga[cf][r] + bsrc[r] + gsrc[(size_t)b * 4 * N + (size_t)r * N + n];
                float mx = fmaxf(fmaxf(a[0], a[1]), fmaxf(a[2], a[3]));
                float e = 0.f;
#pragma unroll
                for (int r = 0; r < 4; ++r) e += __expf(a[r] - mx);
                float p0 = __expf(a[0] - mx) / e;
                if (quad == 0) {
                    sq_lds[cf * 16 + col] = p0;
                    if (mq == 0) sqg[b * N + n] = p0;
                } else {
                    sk_lds[cf * 16 + col] = p0;
                }
            }
        }
    }
    __syncthreads();

    // ---- GEMM: this block's 192-row M quarter; 3 A-frags x 4 B-frags ----
    const short* Ws = reinterpret_cast<const short*>(Wb);
    const int mbase = mq * 192 + wave * 48;
    f32x4 acc[3][4] = {};
#pragma unroll
    for (int k0 = 0; k0 < 256; k0 += 32) {
        short8 bfr[4];
#pragma unroll
        for (int cf = 0; cf < 4; ++cf)
            bfr[cf] = *reinterpret_cast<const short8*>(&T[(cf * 16 + col) * TS + k0 + quad * 8]);
#pragma unroll
        for (int i = 0; i < 3; ++i) {
            int m = mbase + i * 16;
            const short* wr = Ws + (size_t)(m >> 8) * 65536
                              + (size_t)((m & 255) + col) * 256 + k0 + quad * 8;
            short8 af = *reinterpret_cast<const short8*>(wr);
#pragma unroll
            for (int cf = 0; cf < 4; ++cf)
                acc[i][cf] = __builtin_amdgcn_mfma_f32_16x16x32_bf16(af, bfr[cf], acc[i][cf], 0, 0, 0);
        }
    }
    // epilogue (per-frag mat handles quarters spanning matrix boundaries)
#pragma unroll
    for (int i = 0; i < 3; ++i) {
        int m = mbase + i * 16;
        int mat = m >> 8;
        int cr  = (m & 255) + quad * 4;
        const float* bb = (mat == 0) ? bq : (mat == 1) ? bk : bv;
        float bias[4];
#pragma unroll
        for (int r = 0; r < 4; ++r) bias[r] = bb[cr + r];
        if (mat < 2) {
            short* op = reinterpret_cast<short*>((mat == 0) ? qo : ko) + (size_t)b * N * C;
#pragma unroll
            for (int cf = 0; cf < 4; ++cf) {
                int n = n0 + cf * 16 + col;
                float g = (mat == 0) ? sq_lds[cf * 16 + col] * SCALE
                                     : sk_lds[cf * 16 + col];
                sh4 pack;
#pragma unroll
                for (int r = 0; r < 4; ++r) pack[r] = f2bfs((acc[i][cf][r] + bias[r]) * g);
                *reinterpret_cast<sh4*>(op + (size_t)n * C + cr) = pack;
            }
        } else {
            bf16* op = vo + (size_t)b * C * N;
#pragma unroll
            for (int cf = 0; cf < 4; ++cf) {
                int n = n0 + cf * 16 + col;
#pragma unroll
                for (int r = 0; r < 4; ++r)
                    op[(size_t)(cr + r) * N + n] = __float2bfloat16(acc[i][cf][r] + bias[r]);
            }
        }
    }
}

// ---------------------------------------------------------------------------
// K2: attention + gated mix with double-buffered K/V LDS staging
// (R18-verified, unchanged). 512 blocks = (b, head, 128-q tile), 2/CU.
// ---------------------------------------------------------------------------
__global__ __launch_bounds__(256) void k_attn6(
    const bf16* __restrict__ qo, const bf16* __restrict__ ko,
    const bf16* __restrict__ vo, const float* __restrict__ sqg,
    bf16* __restrict__ gt)
{
    __shared__ short P_lds[4][32 * 72];   // 36.9 KB
    __shared__ short K_lds[2][64 * 40];   // 10.2 KB
    __shared__ short V_lds[2][32 * 72];   //  9.2 KB  (total 56.3 KB)

    const int tid  = threadIdx.x;
    const int wave = tid >> 6;
    const int lane = tid & 63;
    const int col  = lane & 15;
    const int quad = lane >> 4;

    const int b = blockIdx.x >> 6;
    const int h = (blockIdx.x >> 3) & 7;
    const int qbase = (blockIdx.x & 7) * 128 + wave * 32;

    const int skey = tid >> 2;          // 0..63
    const int sd   = (tid & 3) * 8;     // 0,8,16,24
    const int svd  = tid >> 3;          // 0..31
    const int svk  = (tid & 7) * 8;     // 0..56

    const short* kgp = reinterpret_cast<const short*>(ko) + (size_t)b * N * C + h * HD;
    const short* vgp = reinterpret_cast<const short*>(vo) + (size_t)b * C * N + (size_t)h * HD * N;
    const short* vp  = vgp;

    short8 qf[2];
    {
        const short* qp = reinterpret_cast<const short*>(qo) + (size_t)b * N * C + h * HD + quad * 8;
#pragma unroll
        for (int g = 0; g < 2; ++g)
            qf[g] = *reinterpret_cast<const short8*>(qp + (size_t)(qbase + g * 16 + col) * C);
    }

    float l[2] = {};
    f32x4 oac[2][2] = {};   // [g][dh]
    short* P = P_lds[wave];

    short8 kstage = *reinterpret_cast<const short8*>(kgp + (size_t)skey * C + sd);
    short8 vstage = *reinterpret_cast<const short8*>(vgp + (size_t)svd * N + svk);
    *reinterpret_cast<short8*>(&K_lds[0][skey * 40 + sd]) = kstage;
    *reinterpret_cast<short8*>(&V_lds[0][svd * 72 + svk]) = vstage;
    __syncthreads();

    for (int t = 0; t < 16; ++t) {
        const int tn = (t + 1) & 15;
        kstage = *reinterpret_cast<const short8*>(kgp + (size_t)(tn * 64 + skey) * C + sd);
        vstage = *reinterpret_cast<const short8*>(vgp + (size_t)svd * N + tn * 64 + svk);

        const short* Kb = K_lds[t & 1];
        const short* Vb = V_lds[t & 1];

        short8 kf[4];
#pragma unroll
        for (int c = 0; c < 4; ++c)
            kf[c] = *reinterpret_cast<const short8*>(&Kb[(c * 16 + col) * 40 + quad * 8]);

#pragma unroll
        for (int g = 0; g < 2; ++g) {
            float s[16];
#pragma unroll
            for (int c = 0; c < 4; ++c) {
                f32x4 acc = {};
                acc = __builtin_amdgcn_mfma_f32_16x16x32_bf16(kf[c], qf[g], acc, 0, 0, 0);
#pragma unroll
                for (int r = 0; r < 4; ++r) s[c * 4 + r] = acc[r];
            }
            float p[16], lloc = 0.f;
#pragma unroll
            for (int i = 0; i < 16; ++i) { p[i] = __expf(s[i]); lloc += p[i]; }
            lloc += __shfl_xor(lloc, 16, 64);
            lloc += __shfl_xor(lloc, 32, 64);
            l[g] += lloc;
#pragma unroll
            for (int c = 0; c < 4; ++c) {
                sh4 pk;
#pragma unroll
                for (int r = 0; r < 4; ++r) pk[r] = f2bfs(p[c * 4 + r]);
                *reinterpret_cast<sh4*>(&P[(g * 16 + col) * 72 + c * 16 + quad * 4]) = pk;
            }
        }

#pragma unroll
        for (int kg = 0; kg < 2; ++kg) {
            short8 vf[2];
#pragma unroll
            for (int dh = 0; dh < 2; ++dh)
                vf[dh] = *reinterpret_cast<const short8*>(&Vb[(dh * 16 + col) * 72 + kg * 32 + quad * 8]);
#pragma unroll
            for (int g = 0; g < 2; ++g) {
                short8 pf = *reinterpret_cast<const short8*>(&P[(g * 16 + col) * 72 + kg * 32 + quad * 8]);
#pragma unroll
                for (int dh = 0; dh < 2; ++dh)
                    oac[g][dh] = __builtin_amdgcn_mfma_f32_16x16x32_bf16(vf[dh], pf, oac[g][dh], 0, 0, 0);
            }
        }

        *reinterpret_cast<short8*>(&K_lds[(t + 1) & 1][skey * 40 + sd]) = kstage;
        *reinterpret_cast<short8*>(&V_lds[(t + 1) & 1][svd * 72 + svk]) = vstage;
        __syncthreads();
    }

    // epilogue: gated mix, pixel-major packed stores
#pragma unroll
    for (int g = 0; g < 2; ++g) {
        const int q = qbase + g * 16 + col;
        const float invl = 1.f / l[g];
        const float sqv  = sqg[b * N + q];
        const float hv   = 1.f - sqv;
        short* gp = reinterpret_cast<short*>(gt) + ((size_t)b * N + q) * C + h * HD + quad * 4;
#pragma unroll
        for (int dh = 0; dh < 2; ++dh) {
            sh4 pack;
#pragma unroll
            for (int r = 0; r < 4; ++r) {
                int d = dh * 16 + quad * 4 + r;
                float vb = bf2f(*reinterpret_cast<const bf16*>(vp + (size_t)d * N + q));
                pack[r] = f2bfs(sqv * (oac[g][dh][r] * invl) + hv * vb);
            }
            *reinterpret_cast<sh4*>(gp + dh * 16) = pack;
        }
    }
}

// ---------------------------------------------------------------------------
// K3: projection MFMA GEMM with gt tile staged in LDS (B-frags were 4x
// redundant across waves). grid (2, 32, 8) = 512 blocks = 2/CU;
// block = 128m x 32n; per wave per k-step: 2 A-global + 2 B-LDS : 4 MFMAs.
// ---------------------------------------------------------------------------
__global__ __launch_bounds__(256) void k_projm4(
    const bf16* __restrict__ gt, const bf16* __restrict__ Wpb,
    const float* __restrict__ bp, float* __restrict__ out)
{
    __shared__ short G[32 * TS];   // [pixel][c], 16.9 KB

    const int tid  = threadIdx.x;
    const int wave = tid >> 6, lane = tid & 63;
    const int col  = lane & 15, quad = lane >> 4;
    const int mrow = blockIdx.x * 128 + wave * 32;   // wave owns 32 m rows
    const int b    = blockIdx.z;
    const int n0   = blockIdx.y * 32;

    // ---- stage gt tile: 32 pixels x 256 c (no transpose, no convert) ----
    {
        const short* gp = reinterpret_cast<const short*>(gt) + ((size_t)b * N + n0) * C;
        const int px = tid >> 3;          // 0..31
        const int c0 = (tid & 7) * 32;    // 0..224
#pragma unroll
        for (int j = 0; j < 4; ++j) {
            short8 v = *reinterpret_cast<const short8*>(gp + (size_t)px * C + c0 + j * 8);
            *reinterpret_cast<short8*>(&G[px * TS + c0 + j * 8]) = v;
        }
    }
    __syncthreads();

    const short* Wm = reinterpret_cast<const short*>(Wpb);

    f32x4 acc[2][2] = {};   // [mfrag][nfrag]
#pragma unroll
    for (int k0 = 0; k0 < 256; k0 += 32) {
        short8 af[2];
#pragma unroll
        for (int mi = 0; mi < 2; ++mi)
            af[mi] = *reinterpret_cast<const short8*>(Wm + (size_t)(mrow + mi * 16 + col) * 256 + k0 + quad * 8);
        short8 bfr[2];
#pragma unroll
        for (int cf = 0; cf < 2; ++cf)
            bfr[cf] = *reinterpret_cast<const short8*>(&G[(cf * 16 + col) * TS + k0 + quad * 8]);
#pragma unroll
        for (int mi = 0; mi < 2; ++mi)
#pragma unroll
            for (int cf = 0; cf < 2; ++cf)
                acc[mi][cf] = __builtin_amdgcn_mfma_f32_16x16x32_bf16(af[mi], bfr[cf], acc[mi][cf], 0, 0, 0);
    }

    float* op = out + (size_t)b * C * N;
#pragma unroll
    for (int mi = 0; mi < 2; ++mi) {
        int cr = mrow + mi * 16 + quad * 4;
        float bias[4];
#pragma unroll
        for (int r = 0; r < 4; ++r) bias[r] = bp[cr + r];
#pragma unroll
        for (int cf = 0; cf < 2; ++cf) {
            int n = n0 + cf * 16 + col;
#pragma unroll
            for (int r = 0; r < 4; ++r)
                op[(size_t)(cr + r) * N + n] = acc[mi][cf][r] + bias[r];
        }
    }
}

// ---------------------------------------------------------------------------
// Workspace (bytes):
//   [0, 32K)        sqg f32 [8][1024]
//   [32K, 544K)     Wb bf16 [4][256][256]  (q,k,v,p)
//   [544K, +4M)     qo bf16 [8][1024][256] (pixel-major, sq*SCALE folded)
//   +4M             ko bf16 [8][1024][256] (pixel-major, sk folded)
//   +4M             vo bf16 [8][256][1024] (d-major)
//   +4M             gt bf16 [8][1024][256] (gated rows, pixel-major)
// ---------------------------------------------------------------------------
extern "C" void kernel_launch(void* const* d_in, const int* in_sizes, int n_in,
                              void* d_out, int out_size, void* d_ws, size_t ws_size,
                              hipStream_t stream)
{
    const float* x   = (const float*)d_in[0];
    const float* gq  = (const float*)d_in[1];
    const float* gk  = (const float*)d_in[2];
    const float* Wsq = (const float*)d_in[3];
    const float* bsq = (const float*)d_in[4];
    const float* Wsk = (const float*)d_in[5];
    const float* bsk = (const float*)d_in[6];
    const float* Wq  = (const float*)d_in[7];
    const float* bq  = (const float*)d_in[8];
    const float* Wk  = (const float*)d_in[9];
    const float* bk  = (const float*)d_in[10];
    const float* Wv  = (const float*)d_in[11];
    const float* bv  = (const float*)d_in[12];
    const float* Wp  = (const float*)d_in[13];
    const float* bp  = (const float*)d_in[14];

    char* ws = (char*)d_ws;
    float* sqg = (float*)ws;
    bf16* Wb   = (bf16*)(ws + 32768);
    bf16* qo   = (bf16*)(ws + 32768 + 524288);
    bf16* ko   = qo + (size_t)Bn * N * C;
    bf16* vo   = ko + (size_t)Bn * N * C;
    bf16* gt   = vo + (size_t)Bn * C * N;
    float* out = (float*)d_out;

    k_prep<<<16, 256, 0, stream>>>(Wq, Wk, Wv, Wp, Wb);
    k_fused5<<<512, 256, 0, stream>>>(x, gq, gk, Wsq, bsq, Wsk, bsk,
                                      Wb, bq, bk, bv, qo, ko, vo, sqg);
    k_attn6<<<512, 256, 0, stream>>>(qo, ko, vo, sqg, gt);
    k_projm4<<<dim3(2, 32, 8), 256, 0, stream>>>(gt, Wb + 3 * 65536, bp, out);
}

// Round 20
// 135.338 us; speedup vs baseline: 1.2822x; 1.0002x over previous
//
#include <hip/hip_runtime.h>
#include <hip/hip_bf16.h>

typedef __hip_bfloat16 bf16;
typedef __attribute__((ext_vector_type(8))) short short8;
typedef __attribute__((ext_vector_type(4))) short sh4;
typedef __attribute__((ext_vector_type(4))) float f32x4;

static __device__ __forceinline__ float bf2f(bf16 h) { return __bfloat162float(h); }
static __device__ __forceinline__ short f2bfs(float f) {
    bf16 h = __float2bfloat16(f);
    return *reinterpret_cast<short*>(&h);
}
static __device__ __forceinline__ short8 cvt8(float4 a, float4 b) {
    short8 o;
    o[0] = f2bfs(a.x); o[1] = f2bfs(a.y); o[2] = f2bfs(a.z); o[3] = f2bfs(a.w);
    o[4] = f2bfs(b.x); o[5] = f2bfs(b.y); o[6] = f2bfs(b.z); o[7] = f2bfs(b.w);
    return o;
}

constexpr int Bn = 8;
constexpr int C  = 256;
constexpr int N  = 1024;     // H*W
constexpr int NH = 8;
constexpr int HD = 32;
constexpr int TS = 264;      // LDS tile stride (shorts)
constexpr float SCALE = 0.17677669529663687f;  // 1/sqrt(32)

// ---------------------------------------------------------------------------
// K0: convert Wq|Wk|Wv|Wp f32 -> Wb bf16 [4][256][256]. 16 blocks.
// ---------------------------------------------------------------------------
__global__ __launch_bounds__(256) void k_prep(
    const float* __restrict__ Wq, const float* __restrict__ Wk,
    const float* __restrict__ Wv, const float* __restrict__ Wp,
    bf16* __restrict__ Wb)
{
    const int tid = threadIdx.x;
    const int mat = blockIdx.x >> 2, seg = blockIdx.x & 3;
    const float* src = (mat == 0) ? Wq : (mat == 1) ? Wk : (mat == 2) ? Wv : Wp;
    short* dst = reinterpret_cast<short*>(Wb) + (size_t)mat * 256 * 256;
#pragma unroll
    for (int i = 0; i < 16; ++i) {
        int f4 = seg * 4096 + i * 256 + tid;
        float4 v = reinterpret_cast<const float4*>(src)[f4];
        sh4 o;
        o[0] = f2bfs(v.x); o[1] = f2bfs(v.y); o[2] = f2bfs(v.z); o[3] = f2bfs(v.w);
        *reinterpret_cast<sh4*>(dst + (size_t)f4 * 4) = o;
    }
}

// ---------------------------------------------------------------------------
// K1: fused transpose + gates + q/k/v GEMM (R17/R18/R19-verified, unchanged).
// 512 blocks = (b, 64-px tile, m-quarter), 3 A-loads : 12 MFMAs per k-step.
// ---------------------------------------------------------------------------
__global__ __launch_bounds__(256) void k_fused5(
    const float* __restrict__ x, const float* __restrict__ gq, const float* __restrict__ gk,
    const float* __restrict__ Wsq, const float* __restrict__ bsq,
    const float* __restrict__ Wsk, const float* __restrict__ bsk,
    const bf16* __restrict__ Wb,
    const float* __restrict__ bq, const float* __restrict__ bk, const float* __restrict__ bv,
    bf16* __restrict__ qo, bf16* __restrict__ ko, bf16* __restrict__ vo,
    float* __restrict__ sqg)
{
    __shared__ short T[64 * TS];     // [pixel][c], 33.8 KB
    __shared__ float sq_lds[64];
    __shared__ float sk_lds[64];

    const int tid  = threadIdx.x;
    const int wave = tid >> 6;
    const int lane = tid & 63;
    const int col  = lane & 15;
    const int quad = lane >> 4;

    const int b    = blockIdx.x >> 6;
    const int rest = blockIdx.x & 63;
    const int n0   = (rest >> 2) * 64;   // 16 tiles of 64 px
    const int mq   = rest & 3;           // m-quarter (192 rows)

    // ---- stage x^T tile: 256 c-rows x 64 pixels ----
    {
        const float* xp = x + (size_t)b * C * N + n0;
        const int row = tid >> 4;        // 0..15 (c within pass)
        const int f   = tid & 15;        // float4 within 64 pixels
#pragma unroll
        for (int p = 0; p < 16; ++p) {
            int c = p * 16 + row;
            float4 v = *reinterpret_cast<const float4*>(xp + (size_t)c * N + f * 4);
            T[(f * 4 + 0) * TS + c] = f2bfs(v.x);
            T[(f * 4 + 1) * TS + c] = f2bfs(v.y);
            T[(f * 4 + 2) * TS + c] = f2bfs(v.z);
            T[(f * 4 + 3) * TS + c] = f2bfs(v.w);
        }
    }
    __syncthreads();

    // ---- gates (wave 0 only): logits via MFMA over 4 B-frags ----
    if (wave == 0) {
        const float* wsrc = (col < 4) ? (Wsq + col * C) : (Wsk + (col & 3) * C);
        f32x4 ga[4] = {};
#pragma unroll
        for (int k0 = 0; k0 < 256; k0 += 32) {
            float4 w0 = *reinterpret_cast<const float4*>(wsrc + k0 + quad * 8);
            float4 w1 = *reinterpret_cast<const float4*>(wsrc + k0 + quad * 8 + 4);
            short8 af = cvt8(w0, w1);
#pragma unroll
            for (int cf = 0; cf < 4; ++cf) {
                short8 bfr = *reinterpret_cast<const short8*>(&T[(cf * 16 + col) * TS + k0 + quad * 8]);
                ga[cf] = __builtin_amdgcn_mfma_f32_16x16x32_bf16(af, bfr, ga[cf], 0, 0, 0);
            }
        }
        if (quad < 2) {
            const float* bsrc = (quad == 0) ? bsq : bsk;
            const float* gsrc = (quad == 0) ? gq : gk;
#pragma unroll
            for (int cf = 0; cf < 4; ++cf) {
                int n = n0 + cf * 16 + col;
                float a[4];
#pragma unroll
                for (int r = 0; r < 4; ++r)
                    a[r] = ga[cf][r] + bsrc[r] + gsrc[(size_t)b * 4 * N + (size_t)r * N + n];
                float mx = fmaxf(fmaxf(a[0], a[1]), fmaxf(a[2], a[3]));
                float e = 0.f;
#pragma unroll
                for (int r = 0; r < 4; ++r) e += __expf(a[r] - mx);
                float p0 = __expf(a[0] - mx) / e;
                if (quad == 0) {
                    sq_lds[cf * 16 + col] = p0;
                    if (mq == 0) sqg[b * N + n] = p0;
                } else {
                    sk_lds[cf * 16 + col] = p0;
                }
            }
        }
    }
    __syncthreads();

    // ---- GEMM: this block's 192-row M quarter; 3 A-frags x 4 B-frags ----
    const short* Ws = reinterpret_cast<const short*>(Wb);
    const int mbase = mq * 192 + wave * 48;
    f32x4 acc[3][4] = {};
#pragma unroll
    for (int k0 = 0; k0 < 256; k0 += 32) {
        short8 bfr[4];
#pragma unroll
        for (int cf = 0; cf < 4; ++cf)
            bfr[cf] = *reinterpret_cast<const short8*>(&T[(cf * 16 + col) * TS + k0 + quad * 8]);
#pragma unroll
        for (int i = 0; i < 3; ++i) {
            int m = mbase + i * 16;
            const short* wr = Ws + (size_t)(m >> 8) * 65536
                              + (size_t)((m & 255) + col) * 256 + k0 + quad * 8;
            short8 af = *reinterpret_cast<const short8*>(wr);
#pragma unroll
            for (int cf = 0; cf < 4; ++cf)
                acc[i][cf] = __builtin_amdgcn_mfma_f32_16x16x32_bf16(af, bfr[cf], acc[i][cf], 0, 0, 0);
        }
    }
    // epilogue (per-frag mat handles quarters spanning matrix boundaries)
#pragma unroll
    for (int i = 0; i < 3; ++i) {
        int m = mbase + i * 16;
        int mat = m >> 8;
        int cr  = (m & 255) + quad * 4;
        const float* bb = (mat == 0) ? bq : (mat == 1) ? bk : bv;
        float bias[4];
#pragma unroll
        for (int r = 0; r < 4; ++r) bias[r] = bb[cr + r];
        if (mat < 2) {
            short* op = reinterpret_cast<short*>((mat == 0) ? qo : ko) + (size_t)b * N * C;
#pragma unroll
            for (int cf = 0; cf < 4; ++cf) {
                int n = n0 + cf * 16 + col;
                float g = (mat == 0) ? sq_lds[cf * 16 + col] * SCALE
                                     : sk_lds[cf * 16 + col];
                sh4 pack;
#pragma unroll
                for (int r = 0; r < 4; ++r) pack[r] = f2bfs((acc[i][cf][r] + bias[r]) * g);
                *reinterpret_cast<sh4*>(op + (size_t)n * C + cr) = pack;
            }
        } else {
            bf16* op = vo + (size_t)b * C * N;
#pragma unroll
            for (int cf = 0; cf < 4; ++cf) {
                int n = n0 + cf * 16 + col;
#pragma unroll
                for (int r = 0; r < 4; ++r)
                    op[(size_t)(cr + r) * N + n] = __float2bfloat16(acc[i][cf][r] + bias[r]);
            }
        }
    }
}

// ---------------------------------------------------------------------------
// K2: attention + gated mix with double-buffered K/V LDS staging
// (R18/R19-verified, unchanged). 512 blocks = (b, head, 128-q tile), 2/CU.
// ---------------------------------------------------------------------------
__global__ __launch_bounds__(256) void k_attn6(
    const bf16* __restrict__ qo, const bf16* __restrict__ ko,
    const bf16* __restrict__ vo, const float* __restrict__ sqg,
    bf16* __restrict__ gt)
{
    __shared__ short P_lds[4][32 * 72];   // 36.9 KB
    __shared__ short K_lds[2][64 * 40];   // 10.2 KB
    __shared__ short V_lds[2][32 * 72];   //  9.2 KB  (total 56.3 KB)

    const int tid  = threadIdx.x;
    const int wave = tid >> 6;
    const int lane = tid & 63;
    const int col  = lane & 15;
    const int quad = lane >> 4;

    const int b = blockIdx.x >> 6;
    const int h = (blockIdx.x >> 3) & 7;
    const int qbase = (blockIdx.x & 7) * 128 + wave * 32;

    const int skey = tid >> 2;          // 0..63
    const int sd   = (tid & 3) * 8;     // 0,8,16,24
    const int svd  = tid >> 3;          // 0..31
    const int svk  = (tid & 7) * 8;     // 0..56

    const short* kgp = reinterpret_cast<const short*>(ko) + (size_t)b * N * C + h * HD;
    const short* vgp = reinterpret_cast<const short*>(vo) + (size_t)b * C * N + (size_t)h * HD * N;
    const short* vp  = vgp;

    short8 qf[2];
    {
        const short* qp = reinterpret_cast<const short*>(qo) + (size_t)b * N * C + h * HD + quad * 8;
#pragma unroll
        for (int g = 0; g < 2; ++g)
            qf[g] = *reinterpret_cast<const short8*>(qp + (size_t)(qbase + g * 16 + col) * C);
    }

    float l[2] = {};
    f32x4 oac[2][2] = {};   // [g][dh]
    short* P = P_lds[wave];

    short8 kstage = *reinterpret_cast<const short8*>(kgp + (size_t)skey * C + sd);
    short8 vstage = *reinterpret_cast<const short8*>(vgp + (size_t)svd * N + svk);
    *reinterpret_cast<short8*>(&K_lds[0][skey * 40 + sd]) = kstage;
    *reinterpret_cast<short8*>(&V_lds[0][svd * 72 + svk]) = vstage;
    __syncthreads();

    for (int t = 0; t < 16; ++t) {
        const int tn = (t + 1) & 15;
        kstage = *reinterpret_cast<const short8*>(kgp + (size_t)(tn * 64 + skey) * C + sd);
        vstage = *reinterpret_cast<const short8*>(vgp + (size_t)svd * N + tn * 64 + svk);

        const short* Kb = K_lds[t & 1];
        const short* Vb = V_lds[t & 1];

        short8 kf[4];
#pragma unroll
        for (int c = 0; c < 4; ++c)
            kf[c] = *reinterpret_cast<const short8*>(&Kb[(c * 16 + col) * 40 + quad * 8]);

#pragma unroll
        for (int g = 0; g < 2; ++g) {
            float s[16];
#pragma unroll
            for (int c = 0; c < 4; ++c) {
                f32x4 acc = {};
                acc = __builtin_amdgcn_mfma_f32_16x16x32_bf16(kf[c], qf[g], acc, 0, 0, 0);
#pragma unroll
                for (int r = 0; r < 4; ++r) s[c * 4 + r] = acc[r];
            }
            float p[16], lloc = 0.f;
#pragma unroll
            for (int i = 0; i < 16; ++i) { p[i] = __expf(s[i]); lloc += p[i]; }
            lloc += __shfl_xor(lloc, 16, 64);
            lloc += __shfl_xor(lloc, 32, 64);
            l[g] += lloc;
#pragma unroll
            for (int c = 0; c < 4; ++c) {
                sh4 pk;
#pragma unroll
                for (int r = 0; r < 4; ++r) pk[r] = f2bfs(p[c * 4 + r]);
                *reinterpret_cast<sh4*>(&P[(g * 16 + col) * 72 + c * 16 + quad * 4]) = pk;
            }
        }

#pragma unroll
        for (int kg = 0; kg < 2; ++kg) {
            short8 vf[2];
#pragma unroll
            for (int dh = 0; dh < 2; ++dh)
                vf[dh] = *reinterpret_cast<const short8*>(&Vb[(dh * 16 + col) * 72 + kg * 32 + quad * 8]);
#pragma unroll
            for (int g = 0; g < 2; ++g) {
                short8 pf = *reinterpret_cast<const short8*>(&P[(g * 16 + col) * 72 + kg * 32 + quad * 8]);
#pragma unroll
                for (int dh = 0; dh < 2; ++dh)
                    oac[g][dh] = __builtin_amdgcn_mfma_f32_16x16x32_bf16(vf[dh], pf, oac[g][dh], 0, 0, 0);
            }
        }

        *reinterpret_cast<short8*>(&K_lds[(t + 1) & 1][skey * 40 + sd]) = kstage;
        *reinterpret_cast<short8*>(&V_lds[(t + 1) & 1][svd * 72 + svk]) = vstage;
        __syncthreads();
    }

    // epilogue: gated mix, pixel-major packed stores
#pragma unroll
    for (int g = 0; g < 2; ++g) {
        const int q = qbase + g * 16 + col;
        const float invl = 1.f / l[g];
        const float sqv  = sqg[b * N + q];
        const float hv   = 1.f - sqv;
        short* gp = reinterpret_cast<short*>(gt) + ((size_t)b * N + q) * C + h * HD + quad * 4;
#pragma unroll
        for (int dh = 0; dh < 2; ++dh) {
            sh4 pack;
#pragma unroll
            for (int r = 0; r < 4; ++r) {
                int d = dh * 16 + quad * 4 + r;
                float vb = bf2f(*reinterpret_cast<const bf16*>(vp + (size_t)d * N + q));
                pack[r] = f2bfs(sqv * (oac[g][dh][r] * invl) + hv * vb);
            }
            *reinterpret_cast<sh4*>(gp + dh * 16) = pack;
        }
    }
}

// ---------------------------------------------------------------------------
// K3: projection MFMA GEMM, 64m x 64n blocks with staged G tile.
// grid (4, 16, 8) = 512 blocks = 2/CU. Wave = 1 m-frag x 4 n-frags:
// per k-step 1 A-global : 4 B-LDS : 4 MFMAs (0.25 loads/MFMA, was 0.5).
// ---------------------------------------------------------------------------
__global__ __launch_bounds__(256) void k_projm5(
    const bf16* __restrict__ gt, const bf16* __restrict__ Wpb,
    const float* __restrict__ bp, float* __restrict__ out)
{
    __shared__ short G[64 * TS];   // [pixel][c], 33.8 KB

    const int tid  = threadIdx.x;
    const int wave = tid >> 6, lane = tid & 63;
    const int col  = lane & 15, quad = lane >> 4;
    const int mrow = blockIdx.x * 64 + wave * 16;    // wave owns 16 m rows
    const int b    = blockIdx.z;
    const int n0   = blockIdx.y * 64;

    // ---- stage gt tile: 64 pixels x 256 c (no transpose, no convert) ----
    {
        const short* gp = reinterpret_cast<const short*>(gt) + ((size_t)b * N + n0) * C;
        const int px = tid >> 2;          // 0..63
        const int c0 = (tid & 3) * 64;    // 0,64,128,192
#pragma unroll
        for (int j = 0; j < 8; ++j) {
            short8 v = *reinterpret_cast<const short8*>(gp + (size_t)px * C + c0 + j * 8);
            *reinterpret_cast<short8*>(&G[px * TS + c0 + j * 8]) = v;
        }
    }
    __syncthreads();

    const short* Wm = reinterpret_cast<const short*>(Wpb);

    f32x4 acc[4] = {};   // [nfrag]
#pragma unroll
    for (int k0 = 0; k0 < 256; k0 += 32) {
        short8 af = *reinterpret_cast<const short8*>(Wm + (size_t)(mrow + col) * 256 + k0 + quad * 8);
#pragma unroll
        for (int cf = 0; cf < 4; ++cf) {
            short8 bfr = *reinterpret_cast<const short8*>(&G[(cf * 16 + col) * TS + k0 + quad * 8]);
            acc[cf] = __builtin_amdgcn_mfma_f32_16x16x32_bf16(af, bfr, acc[cf], 0, 0, 0);
        }
    }

    const int cr = mrow + quad * 4;
    float bias[4];
#pragma unroll
    for (int r = 0; r < 4; ++r) bias[r] = bp[cr + r];
    float* op = out + (size_t)b * C * N;
#pragma unroll
    for (int cf = 0; cf < 4; ++cf) {
        int n = n0 + cf * 16 + col;
#pragma unroll
        for (int r = 0; r < 4; ++r)
            op[(size_t)(cr + r) * N + n] = acc[cf][r] + bias[r];
    }
}

// ---------------------------------------------------------------------------
// Workspace (bytes):
//   [0, 32K)        sqg f32 [8][1024]
//   [32K, 544K)     Wb bf16 [4][256][256]  (q,k,v,p)
//   [544K, +4M)     qo bf16 [8][1024][256] (pixel-major, sq*SCALE folded)
//   +4M             ko bf16 [8][1024][256] (pixel-major, sk folded)
//   +4M             vo bf16 [8][256][1024] (d-major)
//   +4M             gt bf16 [8][1024][256] (gated rows, pixel-major)
// ---------------------------------------------------------------------------
extern "C" void kernel_launch(void* const* d_in, const int* in_sizes, int n_in,
                              void* d_out, int out_size, void* d_ws, size_t ws_size,
                              hipStream_t stream)
{
    const float* x   = (const float*)d_in[0];
    const float* gq  = (const float*)d_in[1];
    const float* gk  = (const float*)d_in[2];
    const float* Wsq = (const float*)d_in[3];
    const float* bsq = (const float*)d_in[4];
    const float* Wsk = (const float*)d_in[5];
    const float* bsk = (const float*)d_in[6];
    const float* Wq  = (const float*)d_in[7];
    const float* bq  = (const float*)d_in[8];
    const float* Wk  = (const float*)d_in[9];
    const float* bk  = (const float*)d_in[10];
    const float* Wv  = (const float*)d_in[11];
    const float* bv  = (const float*)d_in[12];
    const float* Wp  = (const float*)d_in[13];
    const float* bp  = (const float*)d_in[14];

    char* ws = (char*)d_ws;
    float* sqg = (float*)ws;
    bf16* Wb   = (bf16*)(ws + 32768);
    bf16* qo   = (bf16*)(ws + 32768 + 524288);
    bf16* ko   = qo + (size_t)Bn * N * C;
    bf16* vo   = ko + (size_t)Bn * N * C;
    bf16* gt   = vo + (size_t)Bn * C * N;
    float* out = (float*)d_out;

    k_prep<<<16, 256, 0, stream>>>(Wq, Wk, Wv, Wp, Wb);
    k_fused5<<<512, 256, 0, stream>>>(x, gq, gk, Wsq, bsq, Wsk, bsk,
                                      Wb, bq, bk, bv, qo, ko, vo, sqg);
    k_attn6<<<512, 256, 0, stream>>>(qo, ko, vo, sqg, gt);
    k_projm5<<<dim3(4, 16, 8), 256, 0, stream>>>(gt, Wb + 3 * 65536, bp, out);
}